// Round 9
// baseline (109.067 us; speedup 1.0000x reference)
//
#include <hip/hip_runtime.h>

#define DEV __device__ __forceinline__

typedef __bf16 bf16x8 __attribute__((ext_vector_type(8)));
typedef unsigned short u16x8v __attribute__((ext_vector_type(8)));
typedef float f32x4 __attribute__((ext_vector_type(4)));
typedef float f32x16 __attribute__((ext_vector_type(16)));
typedef unsigned int u32x4v __attribute__((ext_vector_type(4)));
typedef unsigned short u16;
typedef unsigned int u32;

// f32 -> bf16 bits, round-to-nearest-even (pure integer ops; validated R1-R8
// for all signs)
DEV u16 f2bf(float f) {
    u32 u = __builtin_bit_cast(u32, f);
    u = (u + 0x7FFFu + ((u >> 16) & 1u)) >> 16;
    return (u16)u;
}

DEV float bf2f(u16 v) {
    return __builtin_bit_cast(float, (u32)v << 16);
}

DEV bf16x8 ld_bf8(const u16* p) {
    return *reinterpret_cast<const bf16x8*>(p);
}

// 8 consecutive f32 -> bf16x8 via f2bf.
DEV bf16x8 cvt8_rne(float4 a0, float4 a1) {
    u16x8v o;
    o[0] = f2bf(a0.x); o[1] = f2bf(a0.y); o[2] = f2bf(a0.z); o[3] = f2bf(a0.w);
    o[4] = f2bf(a1.x); o[5] = f2bf(a1.y); o[6] = f2bf(a1.z); o[7] = f2bf(a1.w);
    return __builtin_bit_cast(bf16x8, o);
}

// pack two f32 -> one u32 of 2 bf16 (lo = a, hi = b).  Validated ONLY for
// a,b >= 0 (P values) — R7 proved it is NOT equivalent to RNE on signed x.
DEV u32 cvt_pk_bf16(float a, float b) {
    u32 r;
    asm("v_cvt_pk_bf16_f32 %0, %1, %2" : "=v"(r) : "v"(a), "v"(b));
    return r;
}

// ---------------------------------------------------------------------------
// Kernel 1: weight transpose+convert.  W[c][h] f32 -> Wt[w][h][c] bf16.
// Wq pre-scaled by 1/sqrt(512)*log2(e).
// ---------------------------------------------------------------------------
__global__ __launch_bounds__(256) void prep_kernel(const float* __restrict__ W0,
                                                   const float* __restrict__ W1,
                                                   const float* __restrict__ W2,
                                                   u16* __restrict__ Wt) {
    int idx = blockIdx.x * 256 + threadIdx.x;   // 3*64*512 = 98304
    int w = idx >> 15, rem = idx & 32767, h = rem >> 9, c = rem & 511;
    const float* W = (w == 0) ? W0 : ((w == 1) ? W1 : W2);
    float v = W[c * 64 + h];
    if (w == 0) v *= 0.044194173824159216f * 1.4426950408889634f;  // SCL*log2e
    Wt[idx] = f2bf(v);
}

// ---------------------------------------------------------------------------
// Kernel 2: QKV projection via MFMA 16x16x32 bf16, reading x f32 directly.
// 768 blocks: rg = blk/3, mat = blk%3 (3 mats of one rg share x via L2).
// ---------------------------------------------------------------------------
__global__ __launch_bounds__(256) void proj_kernel(const float* __restrict__ x,
                                                   const u16* __restrict__ Wt,
                                                   u16* __restrict__ Q,
                                                   u16* __restrict__ Kq,
                                                   u16* __restrict__ Vt) {
    const int wave = threadIdx.x >> 6, lane = threadIdx.x & 63;
    const int lr = lane & 15, lg = lane >> 4;
    const int mat = blockIdx.x % 3;
    const int rg = blockIdx.x / 3;
    const int r0 = rg * 64 + wave * 16;
    const int grow = r0 + lr;

    f32x4 acc[4];
#pragma unroll
    for (int b = 0; b < 4; ++b) acc[b] = (f32x4){0.f, 0.f, 0.f, 0.f};

#pragma unroll
    for (int kk = 0; kk < 16; ++kk) {
        const float* xp = x + (size_t)grow * 512 + kk * 32 + lg * 8;
        float4 a0 = *reinterpret_cast<const float4*>(xp);
        float4 a1 = *reinterpret_cast<const float4*>(xp + 4);
        bf16x8 af = cvt8_rne(a0, a1);
#pragma unroll
        for (int nt = 0; nt < 4; ++nt) {
            bf16x8 bf = ld_bf8(Wt + mat * 32768 + (lr + 16 * nt) * 512 + kk * 32 + lg * 8);
            acc[nt] = __builtin_amdgcn_mfma_f32_16x16x32_bf16(af, bf, acc[nt], 0, 0, 0);
        }
    }

    if (mat < 2) {
        u16* dst = (mat == 0) ? Q : Kq;
#pragma unroll
        for (int nt = 0; nt < 4; ++nt) {
            const int h = lr + 16 * nt;
#pragma unroll
            for (int reg = 0; reg < 4; ++reg)
                dst[(size_t)(r0 + 4 * lg + reg) * 64 + h] = f2bf(acc[nt][reg]);
        }
    } else {
        const int bidx = r0 >> 12;
        const int t0 = (r0 & 4095) + 4 * lg;
#pragma unroll
        for (int nt = 0; nt < 4; ++nt) {
            const int h = lr + 16 * nt;
            ushort4 hv;
            hv.x = f2bf(acc[nt][0]); hv.y = f2bf(acc[nt][1]);
            hv.z = f2bf(acc[nt][2]); hv.w = f2bf(acc[nt][3]);
            *reinterpret_cast<ushort4*>(Vt + ((size_t)(bidx * 64 + h)) * 4096 + t0) = hv;
        }
    }
}

// ---------------------------------------------------------------------------
// Attention helpers (32x32 swapped-operand; layouts validated R6/R8)
// ---------------------------------------------------------------------------
DEV f32x16 qk_sub(const u16* kp, const bf16x8 (&qf)[4]) {
    f32x16 st;
#pragma unroll
    for (int r = 0; r < 16; ++r) st[r] = 0.f;
#pragma unroll
    for (int kk = 0; kk < 4; ++kk)
        st = __builtin_amdgcn_mfma_f32_32x32x16_bf16(ld_bf8(kp + kk * 16), qf[kk], st, 0, 0, 0);
    return st;
}

DEV void mask_diag(f32x16& st, int q31, int hi) {
#pragma unroll
    for (int reg = 0; reg < 16; ++reg) {
        const int crow = (reg & 3) + 8 * (reg >> 2) + 4 * hi;
        if (crow > q31) st[reg] = -3.0e38f;
    }
}

// max over 16 regs, shaped for v_max3 fusion (8 ops)
DEV float max16(const f32x16& a) {
    float m0 = fmaxf(fmaxf(a[0], a[1]), a[2]);
    float m1 = fmaxf(fmaxf(a[3], a[4]), a[5]);
    float m2 = fmaxf(fmaxf(a[6], a[7]), a[8]);
    float m3 = fmaxf(fmaxf(a[9], a[10]), a[11]);
    float m4 = fmaxf(fmaxf(a[12], a[13]), a[14]);
    float m5 = fmaxf(fmaxf(m0, m1), a[15]);
    float m6 = fmaxf(fmaxf(m2, m3), m4);
    return fmaxf(m5, m6);
}

// st = exp2(st - m); returns 4-chain partial sum
DEV float expsum(f32x16& st, float m) {
    float r0 = 0.f, r1 = 0.f, r2 = 0.f, r3 = 0.f;
#pragma unroll
    for (int g = 0; g < 4; ++g) {
        float p0 = exp2f(st[4 * g + 0] - m);
        float p1 = exp2f(st[4 * g + 1] - m);
        float p2 = exp2f(st[4 * g + 2] - m);
        float p3 = exp2f(st[4 * g + 3] - m);
        st[4 * g + 0] = p0; st[4 * g + 1] = p1;
        st[4 * g + 2] = p2; st[4 * g + 3] = p3;
        r0 += p0; r1 += p1; r2 += p2; r3 += p3;
    }
    return (r0 + r1) + (r2 + r3);
}

// P^T registers -> two B-fragments for PV.  8 cvt_pk + 4 shfl_xor + selects.
// (key map verified R6: hi=0: pb0 = {A0,A1,pA0,pA1}; hi=1: pb0 = {pA2,pA3,A2,A3};
//  pb1 analogous with A4..A7.)
DEV void packP(const f32x16& st, bf16x8& pb0, bf16x8& pb1, int hi) {
    u32 A0 = cvt_pk_bf16(st[0], st[1]),  A1 = cvt_pk_bf16(st[2], st[3]);
    u32 A2 = cvt_pk_bf16(st[4], st[5]),  A3 = cvt_pk_bf16(st[6], st[7]);
    u32 A4 = cvt_pk_bf16(st[8], st[9]),  A5 = cvt_pk_bf16(st[10], st[11]);
    u32 A6 = cvt_pk_bf16(st[12], st[13]), A7 = cvt_pk_bf16(st[14], st[15]);
    u32 e0 = __shfl_xor(hi ? A0 : A2, 32, 64);
    u32 e1 = __shfl_xor(hi ? A1 : A3, 32, 64);
    u32 e2 = __shfl_xor(hi ? A4 : A6, 32, 64);
    u32 e3 = __shfl_xor(hi ? A5 : A7, 32, 64);
    u32x4v w0, w1;
    w0[0] = hi ? e0 : A0;
    w0[1] = hi ? e1 : A1;
    w0[2] = hi ? A2 : e0;
    w0[3] = hi ? A3 : e1;
    w1[0] = hi ? e2 : A4;
    w1[1] = hi ? e3 : A5;
    w1[2] = hi ? A6 : e2;
    w1[3] = hi ? A7 : e3;
    pb0 = __builtin_bit_cast(bf16x8, w0);
    pb1 = __builtin_bit_cast(bf16x8, w1);
}

DEV void pv(const u16* vp, const bf16x8& pb0, const bf16x8& pb1,
            f32x16& o0, f32x16& o1) {
    bf16x8 v00 = ld_bf8(vp);
    bf16x8 v01 = ld_bf8(vp + 16);
    bf16x8 v10 = ld_bf8(vp + 32 * 4096);
    bf16x8 v11 = ld_bf8(vp + 32 * 4096 + 16);
    o0 = __builtin_amdgcn_mfma_f32_32x32x16_bf16(v00, pb0, o0, 0, 0, 0);
    o0 = __builtin_amdgcn_mfma_f32_32x32x16_bf16(v01, pb1, o0, 0, 0, 0);
    o1 = __builtin_amdgcn_mfma_f32_32x32x16_bf16(v10, pb0, o1, 0, 0, 0);
    o1 = __builtin_amdgcn_mfma_f32_32x32x16_bf16(v11, pb1, o1, 0, 0, 0);
}

// ---------------------------------------------------------------------------
// Kernel 3: causal flash attention, swapped-operand 32x32, zero LDS,
// 1 wave/block, 4-WAY ILP: each outer iteration covers 128 keys as four
// independent 32-key chains (st0..st3) sharing one rescale check.
// Decode bijective over (tile, c); b = bid&3 spreads batches across XCDs.
// Partials stored as bf16.
// ---------------------------------------------------------------------------
__global__ __launch_bounds__(64) void attn_part_kernel(const u16* __restrict__ Q,
                                                       const u16* __restrict__ K,
                                                       const u16* __restrict__ Vt,
                                                       u16* __restrict__ Opart,
                                                       float* __restrict__ Mpart,
                                                       float* __restrict__ Lpart,
                                                       int SPLIT, int CT) {
    const int lane = threadIdx.x;
    const int q31 = lane & 31, hi = lane >> 5;
    const int bid = blockIdx.x;
    const int tile = ((bid & 3) << 7) | ((bid >> 2) & 127);
    const int c = bid >> 9;
    const int b = tile >> 7, qi = tile & 127;
    const int qr0 = qi * 32;
    const int nkv = qi + 1;                   // 32-key subtiles for this q-tile
    const int s0 = c * CT;
    if (s0 >= nkv) return;
    const int s1 = min(nkv, s0 + CT);

    const u16* Qb = Q + (size_t)b * 4096 * 64;
    const u16* Kb = K + (size_t)b * 4096 * 64;
    const u16* Vb = Vt + (size_t)b * 64 * 4096;

    bf16x8 qf[4];
#pragma unroll
    for (int kk = 0; kk < 4; ++kk)
        qf[kk] = ld_bf8(Qb + (size_t)(qr0 + q31) * 64 + kk * 16 + hi * 8);

    f32x16 o0, o1;
#pragma unroll
    for (int r = 0; r < 16; ++r) { o0[r] = 0.f; o1[r] = 0.f; }
    float m_run = -1.0e30f, l_run = 0.f;

    for (int s = s0; s < s1; s += 4) {
        const int rem = s1 - s;               // >= 1
        const int kv0 = s * 32;
        const u16* kp = Kb + (size_t)(kv0 + q31) * 64 + hi * 8;

        f32x16 st0 = qk_sub(kp, qf);
        f32x16 st1, st2, st3;
        if (rem > 1) st1 = qk_sub(kp + 2048, qf);
        if (rem > 2) st2 = qk_sub(kp + 4096, qf);
        if (rem > 3) st3 = qk_sub(kp + 6144, qf);

        // causal mask: only the diagonal subtile (index qi) needs it
        if (s == qi) mask_diag(st0, q31, hi);
        if (rem > 1 && s + 1 == qi) mask_diag(st1, q31, hi);
        if (rem > 2 && s + 2 == qi) mask_diag(st2, q31, hi);
        if (rem > 3 && s + 3 == qi) mask_diag(st3, q31, hi);

        float pm = max16(st0);
        if (rem > 1) pm = fmaxf(pm, max16(st1));
        if (rem > 2) pm = fmaxf(pm, max16(st2));
        if (rem > 3) pm = fmaxf(pm, max16(st3));
        pm = fmaxf(pm, __shfl_xor(pm, 32, 64));

        // defer-rescale (THR = 11.5 log2-units)
        if (!__all(pm - m_run <= 11.5f)) {
            float mn = fmaxf(m_run, pm);
            float al = exp2f(m_run - mn);
            m_run = mn;
            l_run *= al;
#pragma unroll
            for (int r = 0; r < 16; ++r) { o0[r] *= al; o1[r] *= al; }
        }

        float rs = expsum(st0, m_run);
        if (rem > 1) rs += expsum(st1, m_run);
        if (rem > 2) rs += expsum(st2, m_run);
        if (rem > 3) rs += expsum(st3, m_run);
        rs += __shfl_xor(rs, 32, 64);
        l_run += rs;

        const u16* vp = Vb + (size_t)q31 * 4096 + kv0 + hi * 8;
        bf16x8 p0, p1;
        packP(st0, p0, p1, hi);
        pv(vp, p0, p1, o0, o1);
        if (rem > 1) { packP(st1, p0, p1, hi); pv(vp + 32, p0, p1, o0, o1); }
        if (rem > 2) { packP(st2, p0, p1, hi); pv(vp + 64, p0, p1, o0, o1); }
        if (rem > 3) { packP(st3, p0, p1, hi); pv(vp + 96, p0, p1, o0, o1); }
    }

    // write transposed partials (bf16): Opart[base][d][q]
    const size_t base = (size_t)(tile * SPLIT + c);
    u16* Op = Opart + base * 2048;
#pragma unroll
    for (int reg = 0; reg < 16; ++reg) {
        const int crow = (reg & 3) + 8 * (reg >> 2) + 4 * hi;
        Op[crow * 32 + q31] = f2bf(o0[reg]);
        Op[(32 + crow) * 32 + q31] = f2bf(o1[reg]);
    }
    if (lane < 32) {
        Mpart[base * 32 + lane] = m_run;
        Lpart[base * 32 + lane] = l_run;
    }
}

// ---------------------------------------------------------------------------
// Kernel 4: merge partials (bf16 Opart).  One block per q-tile (512 blocks).
// LDS-staged transpose: global reads 16B-coalesced, pad 33 kills bank
// conflicts, out writes coalesced.
// ---------------------------------------------------------------------------
__global__ __launch_bounds__(256) void merge_kernel(const u16* __restrict__ Opart,
                                                    const float* __restrict__ Mpart,
                                                    const float* __restrict__ Lpart,
                                                    float* __restrict__ out,
                                                    int SPLIT, int CT) {
    __shared__ float ld[64 * 33];
    const int tile = blockIdx.x;            // 0..511
    const int tid = threadIdx.x;
    const int q = tid >> 3, dg = tid & 7;
    const int qi = tile & 127;
    const int nkv = qi + 1;
    int nc = (nkv + CT - 1) / CT;
    if (nc > SPLIT) nc = SPLIT;

    float M = -3.0e38f;
    for (int c = 0; c < nc; ++c)
        M = fmaxf(M, Mpart[(tile * SPLIT + c) * 32 + q]);

    float L = 0.f;
    float acc[8];
#pragma unroll
    for (int j = 0; j < 8; ++j) acc[j] = 0.f;

    for (int c = 0; c < nc; ++c) {
        const size_t base = (size_t)(tile * SPLIT + c);
        // cooperative coalesced load of the 2048-bf16 chunk (4 KB) -> LDS
        u16x8v v = reinterpret_cast<const u16x8v*>(Opart + base * 2048)[tid];
        {
            const int drow = tid >> 2;           // (tid*8)>>5
            const int qq = (tid & 3) * 8;        // (tid*8)&31
            float* dst = &ld[drow * 33 + qq];
#pragma unroll
            for (int j = 0; j < 8; ++j) dst[j] = bf2f(v[j]);
        }
        __syncthreads();
        float w = exp2f(Mpart[base * 32 + q] - M);
        L += w * Lpart[base * 32 + q];
#pragma unroll
        for (int j = 0; j < 8; ++j)
            acc[j] += w * ld[(dg * 8 + j) * 33 + q];
        __syncthreads();
    }

    const float inv = 1.0f / L;
    float4 r0, r1;
    r0.x = acc[0] * inv; r0.y = acc[1] * inv; r0.z = acc[2] * inv; r0.w = acc[3] * inv;
    r1.x = acc[4] * inv; r1.y = acc[5] * inv; r1.z = acc[6] * inv; r1.w = acc[7] * inv;
    float4* dst = reinterpret_cast<float4*>(out + ((size_t)(tile * 32 + q)) * 64 + dg * 8);
    dst[0] = r0;
    dst[1] = r1;
}

// ---------------------------------------------------------------------------
extern "C" void kernel_launch(void* const* d_in, const int* in_sizes, int n_in,
                              void* d_out, int out_size, void* d_ws, size_t ws_size,
                              hipStream_t stream) {
    const float* x  = (const float*)d_in[0];
    const float* Wq = (const float*)d_in[1];
    const float* Wk = (const float*)d_in[2];
    const float* Wv = (const float*)d_in[3];
    float* out = (float*)d_out;

    char* ws = (char*)d_ws;
    const size_t MB = 1024 * 1024;
    u16* Qw  = (u16*)(ws);                     // 2 MiB
    u16* Kw  = (u16*)(ws + 2 * MB);            // 2 MiB
    u16* Vtw = (u16*)(ws + 4 * MB);            // 2 MiB
    u16* Wt  = (u16*)(ws + 6 * MB);            // 96 KiB

    // Opart is bf16 now: SPLIT * 2 MiB.
    int SPLIT = 16;
    while (SPLIT > 1) {
        size_t need = 8 * MB + (size_t)SPLIT * 2 * MB + (size_t)SPLIT * 128 * 1024;
        if (need <= ws_size) break;
        SPLIT >>= 1;
    }
    const int CT = (128 + SPLIT - 1) / SPLIT;

    u16* Opart = (u16*)(ws + 8 * MB);
    float* Mpart = (float*)(ws + 8 * MB + (size_t)SPLIT * 2 * MB);
    float* Lpart = Mpart + (size_t)SPLIT * 512 * 32;

    prep_kernel<<<384, 256, 0, stream>>>(Wq, Wk, Wv, Wt);
    proj_kernel<<<768, 256, 0, stream>>>(x, Wt, Qw, Kw, Vtw);
    attn_part_kernel<<<512 * SPLIT, 64, 0, stream>>>(Qw, Kw, Vtw, Opart, Mpart, Lpart,
                                                     SPLIT, CT);
    merge_kernel<<<512, 256, 0, stream>>>(Opart, Mpart, Lpart, out, SPLIT, CT);
}

// Round 10
// 100.574 us; speedup vs baseline: 1.0844x; 1.0844x over previous
//
#include <hip/hip_runtime.h>

#define DEV __device__ __forceinline__

typedef __bf16 bf16x8 __attribute__((ext_vector_type(8)));
typedef unsigned short u16x8v __attribute__((ext_vector_type(8)));
typedef float f32x4 __attribute__((ext_vector_type(4)));
typedef float f32x16 __attribute__((ext_vector_type(16)));
typedef unsigned int u32x4v __attribute__((ext_vector_type(4)));
typedef unsigned short u16;
typedef unsigned int u32;

// f32 -> bf16 bits, round-to-nearest-even (validated R1-R8, all signs)
DEV u16 f2bf(float f) {
    u32 u = __builtin_bit_cast(u32, f);
    u = (u + 0x7FFFu + ((u >> 16) & 1u)) >> 16;
    return (u16)u;
}

DEV float bf2f(u16 v) {
    return __builtin_bit_cast(float, (u32)v << 16);
}

DEV bf16x8 ld_bf8(const u16* p) {
    return *reinterpret_cast<const bf16x8*>(p);
}

// raw v_exp_f32 (no libm denormal guards) — softmax P in [0,1], fine
DEV float fexp2(float x) { return __builtin_amdgcn_exp2f(x); }

// 8 consecutive f32 -> bf16x8 via f2bf
DEV bf16x8 cvt8_rne(float4 a0, float4 a1) {
    u16x8v o;
    o[0] = f2bf(a0.x); o[1] = f2bf(a0.y); o[2] = f2bf(a0.z); o[3] = f2bf(a0.w);
    o[4] = f2bf(a1.x); o[5] = f2bf(a1.y); o[6] = f2bf(a1.z); o[7] = f2bf(a1.w);
    return __builtin_bit_cast(bf16x8, o);
}

// pack two f32 -> one u32 of 2 bf16 (lo=a, hi=b).  Validated ONLY for a,b>=0
// (P values) — R7 proved NOT equivalent to RNE on signed inputs.
DEV u32 cvt_pk_bf16(float a, float b) {
    u32 r;
    asm("v_cvt_pk_bf16_f32 %0, %1, %2" : "=v"(r) : "v"(a), "v"(b));
    return r;
}

// ---------------------------------------------------------------------------
// Kernel 1: weight transpose+convert.  W[c][h] f32 -> Wt[w][h][c] bf16.
// Wq pre-scaled by 1/sqrt(512)*log2(e).
// ---------------------------------------------------------------------------
__global__ __launch_bounds__(256) void prep_kernel(const float* __restrict__ W0,
                                                   const float* __restrict__ W1,
                                                   const float* __restrict__ W2,
                                                   u16* __restrict__ Wt) {
    int idx = blockIdx.x * 256 + threadIdx.x;   // 3*64*512 = 98304
    int w = idx >> 15, rem = idx & 32767, h = rem >> 9, c = rem & 511;
    const float* W = (w == 0) ? W0 : ((w == 1) ? W1 : W2);
    float v = W[c * 64 + h];
    if (w == 0) v *= 0.044194173824159216f * 1.4426950408889634f;  // SCL*log2e
    Wt[idx] = f2bf(v);
}

// ---------------------------------------------------------------------------
// Kernel 2: QKV projection via MFMA 16x16x32 bf16, reading x f32 directly.
// 768 blocks: rg = blk/3, mat = blk%3 (3 mats of one rg share x via L2).
// ---------------------------------------------------------------------------
__global__ __launch_bounds__(256) void proj_kernel(const float* __restrict__ x,
                                                   const u16* __restrict__ Wt,
                                                   u16* __restrict__ Q,
                                                   u16* __restrict__ Kq,
                                                   u16* __restrict__ Vt) {
    const int wave = threadIdx.x >> 6, lane = threadIdx.x & 63;
    const int lr = lane & 15, lg = lane >> 4;
    const int mat = blockIdx.x % 3;
    const int rg = blockIdx.x / 3;
    const int r0 = rg * 64 + wave * 16;
    const int grow = r0 + lr;

    f32x4 acc[4];
#pragma unroll
    for (int b = 0; b < 4; ++b) acc[b] = (f32x4){0.f, 0.f, 0.f, 0.f};

#pragma unroll
    for (int kk = 0; kk < 16; ++kk) {
        const float* xp = x + (size_t)grow * 512 + kk * 32 + lg * 8;
        float4 a0 = *reinterpret_cast<const float4*>(xp);
        float4 a1 = *reinterpret_cast<const float4*>(xp + 4);
        bf16x8 af = cvt8_rne(a0, a1);
#pragma unroll
        for (int nt = 0; nt < 4; ++nt) {
            bf16x8 bf = ld_bf8(Wt + mat * 32768 + (lr + 16 * nt) * 512 + kk * 32 + lg * 8);
            acc[nt] = __builtin_amdgcn_mfma_f32_16x16x32_bf16(af, bf, acc[nt], 0, 0, 0);
        }
    }

    if (mat < 2) {
        u16* dst = (mat == 0) ? Q : Kq;
#pragma unroll
        for (int nt = 0; nt < 4; ++nt) {
            const int h = lr + 16 * nt;
#pragma unroll
            for (int reg = 0; reg < 4; ++reg)
                dst[(size_t)(r0 + 4 * lg + reg) * 64 + h] = f2bf(acc[nt][reg]);
        }
    } else {
        const int bidx = r0 >> 12;
        const int t0 = (r0 & 4095) + 4 * lg;
#pragma unroll
        for (int nt = 0; nt < 4; ++nt) {
            const int h = lr + 16 * nt;
            ushort4 hv;
            hv.x = f2bf(acc[nt][0]); hv.y = f2bf(acc[nt][1]);
            hv.z = f2bf(acc[nt][2]); hv.w = f2bf(acc[nt][3]);
            *reinterpret_cast<ushort4*>(Vt + ((size_t)(bidx * 64 + h)) * 4096 + t0) = hv;
        }
    }
}

// ---------------------------------------------------------------------------
// Attention helpers (32x32 swapped-operand; layouts validated R6/R8)
// ---------------------------------------------------------------------------
DEV f32x16 qk_sub(const u16* kp, const bf16x8 (&qf)[4]) {
    f32x16 st;
#pragma unroll
    for (int r = 0; r < 16; ++r) st[r] = 0.f;
#pragma unroll
    for (int kk = 0; kk < 4; ++kk)
        st = __builtin_amdgcn_mfma_f32_32x32x16_bf16(ld_bf8(kp + kk * 16), qf[kk], st, 0, 0, 0);
    return st;
}

DEV void mask_diag(f32x16& st, int q31, int hi) {
#pragma unroll
    for (int reg = 0; reg < 16; ++reg) {
        const int crow = (reg & 3) + 8 * (reg >> 2) + 4 * hi;
        if (crow > q31) st[reg] = -3.0e38f;
    }
}

// max over 16 regs, shaped for v_max3 fusion (8 ops)
DEV float max16(const f32x16& a) {
    float m0 = fmaxf(fmaxf(a[0], a[1]), a[2]);
    float m1 = fmaxf(fmaxf(a[3], a[4]), a[5]);
    float m2 = fmaxf(fmaxf(a[6], a[7]), a[8]);
    float m3 = fmaxf(fmaxf(a[9], a[10]), a[11]);
    float m4 = fmaxf(fmaxf(a[12], a[13]), a[14]);
    float m5 = fmaxf(fmaxf(m0, m1), a[15]);
    float m6 = fmaxf(fmaxf(m2, m3), m4);
    return fmaxf(m5, m6);
}

// st = exp2(st - m) via raw v_exp_f32; returns 4-chain partial sum
DEV float expsum(f32x16& st, float m) {
    float r0 = 0.f, r1 = 0.f, r2 = 0.f, r3 = 0.f;
#pragma unroll
    for (int g = 0; g < 4; ++g) {
        float p0 = fexp2(st[4 * g + 0] - m);
        float p1 = fexp2(st[4 * g + 1] - m);
        float p2 = fexp2(st[4 * g + 2] - m);
        float p3 = fexp2(st[4 * g + 3] - m);
        st[4 * g + 0] = p0; st[4 * g + 1] = p1;
        st[4 * g + 2] = p2; st[4 * g + 3] = p3;
        r0 += p0; r1 += p1; r2 += p2; r3 += p3;
    }
    return (r0 + r1) + (r2 + r3);
}

// P^T registers -> two B-fragments for PV.  8 cvt_pk + 4 shfl_xor + selects.
// (key map verified R6: hi=0: pb0 = {A0,A1,pA0,pA1}; hi=1: pb0 = {pA2,pA3,A2,A3};
//  pb1 analogous with A4..A7.)
DEV void packP(const f32x16& st, bf16x8& pb0, bf16x8& pb1, int hi) {
    u32 A0 = cvt_pk_bf16(st[0], st[1]),  A1 = cvt_pk_bf16(st[2], st[3]);
    u32 A2 = cvt_pk_bf16(st[4], st[5]),  A3 = cvt_pk_bf16(st[6], st[7]);
    u32 A4 = cvt_pk_bf16(st[8], st[9]),  A5 = cvt_pk_bf16(st[10], st[11]);
    u32 A6 = cvt_pk_bf16(st[12], st[13]), A7 = cvt_pk_bf16(st[14], st[15]);
    u32 e0 = __shfl_xor(hi ? A0 : A2, 32, 64);
    u32 e1 = __shfl_xor(hi ? A1 : A3, 32, 64);
    u32 e2 = __shfl_xor(hi ? A4 : A6, 32, 64);
    u32 e3 = __shfl_xor(hi ? A5 : A7, 32, 64);
    u32x4v w0, w1;
    w0[0] = hi ? e0 : A0;
    w0[1] = hi ? e1 : A1;
    w0[2] = hi ? A2 : e0;
    w0[3] = hi ? A3 : e1;
    w1[0] = hi ? e2 : A4;
    w1[1] = hi ? e3 : A5;
    w1[2] = hi ? A6 : e2;
    w1[3] = hi ? A7 : e3;
    pb0 = __builtin_bit_cast(bf16x8, w0);
    pb1 = __builtin_bit_cast(bf16x8, w1);
}

DEV void pv(const u16* vp, const bf16x8& pb0, const bf16x8& pb1,
            f32x16& o0, f32x16& o1) {
    bf16x8 v00 = ld_bf8(vp);
    bf16x8 v01 = ld_bf8(vp + 16);
    bf16x8 v10 = ld_bf8(vp + 32 * 4096);
    bf16x8 v11 = ld_bf8(vp + 32 * 4096 + 16);
    o0 = __builtin_amdgcn_mfma_f32_32x32x16_bf16(v00, pb0, o0, 0, 0, 0);
    o0 = __builtin_amdgcn_mfma_f32_32x32x16_bf16(v01, pb1, o0, 0, 0, 0);
    o1 = __builtin_amdgcn_mfma_f32_32x32x16_bf16(v10, pb0, o1, 0, 0, 0);
    o1 = __builtin_amdgcn_mfma_f32_32x32x16_bf16(v11, pb1, o1, 0, 0, 0);
}

// ---------------------------------------------------------------------------
// Kernel 3: causal flash attention, swapped-operand 32x32, zero LDS,
// 1 wave/block, 2-way ILP (R8 structure; R9 proved 4-way costs occupancy).
// Decode bijective over (tile, c); b = bid&3 spreads batches across XCDs.
// Partials stored as bf16.
// ---------------------------------------------------------------------------
__global__ __launch_bounds__(64) void attn_part_kernel(const u16* __restrict__ Q,
                                                       const u16* __restrict__ K,
                                                       const u16* __restrict__ Vt,
                                                       u16* __restrict__ Opart,
                                                       float* __restrict__ Mpart,
                                                       float* __restrict__ Lpart,
                                                       int SPLIT, int CT) {
    const int lane = threadIdx.x;
    const int q31 = lane & 31, hi = lane >> 5;
    const int bid = blockIdx.x;
    const int tile = ((bid & 3) << 7) | ((bid >> 2) & 127);
    const int c = bid >> 9;
    const int b = tile >> 7, qi = tile & 127;
    const int qr0 = qi * 32;
    const int nkv = qi + 1;                   // 32-key subtiles for this q-tile
    const int s0 = c * CT;
    if (s0 >= nkv) return;
    const int s1 = min(nkv, s0 + CT);

    const u16* Qb = Q + (size_t)b * 4096 * 64;
    const u16* Kb = K + (size_t)b * 4096 * 64;
    const u16* Vb = Vt + (size_t)b * 64 * 4096;

    bf16x8 qf[4];
#pragma unroll
    for (int kk = 0; kk < 4; ++kk)
        qf[kk] = ld_bf8(Qb + (size_t)(qr0 + q31) * 64 + kk * 16 + hi * 8);

    f32x16 o0, o1;
#pragma unroll
    for (int r = 0; r < 16; ++r) { o0[r] = 0.f; o1[r] = 0.f; }
    float m_run = -1.0e30f, l_run = 0.f;

    for (int s = s0; s < s1; s += 2) {
        const int kv0 = s * 32;
        const bool hasB = (s + 1 < s1);
        const u16* kpA = Kb + (size_t)(kv0 + q31) * 64 + hi * 8;

        f32x16 stA = qk_sub(kpA, qf);
        f32x16 stB;
        if (hasB) stB = qk_sub(kpA + 2048, qf);

        if (s == qi) mask_diag(stA, q31, hi);
        if (hasB && s + 1 == qi) mask_diag(stB, q31, hi);

        float pm = hasB ? fmaxf(max16(stA), max16(stB)) : max16(stA);
        pm = fmaxf(pm, __shfl_xor(pm, 32, 64));

        // defer-rescale (THR = 11.5 log2-units)
        if (!__all(pm - m_run <= 11.5f)) {
            float mn = fmaxf(m_run, pm);
            float al = fexp2(m_run - mn);
            m_run = mn;
            l_run *= al;
#pragma unroll
            for (int r = 0; r < 16; ++r) { o0[r] *= al; o1[r] *= al; }
        }

        float rs = expsum(stA, m_run);
        if (hasB) rs += expsum(stB, m_run);
        rs += __shfl_xor(rs, 32, 64);
        l_run += rs;

        const u16* vp = Vb + (size_t)q31 * 4096 + kv0 + hi * 8;
        bf16x8 p0, p1;
        packP(stA, p0, p1, hi);
        pv(vp, p0, p1, o0, o1);
        if (hasB) {
            packP(stB, p0, p1, hi);
            pv(vp + 32, p0, p1, o0, o1);
        }
    }

    // write transposed partials (bf16): Opart[base][d][q]
    const size_t base = (size_t)(tile * SPLIT + c);
    u16* Op = Opart + base * 2048;
#pragma unroll
    for (int reg = 0; reg < 16; ++reg) {
        const int crow = (reg & 3) + 8 * (reg >> 2) + 4 * hi;
        Op[crow * 32 + q31] = f2bf(o0[reg]);
        Op[(32 + crow) * 32 + q31] = f2bf(o1[reg]);
    }
    if (lane < 32) {
        Mpart[base * 32 + lane] = m_run;
        Lpart[base * 32 + lane] = l_run;
    }
}

// ---------------------------------------------------------------------------
// Kernel 4: merge partials (bf16 Opart).  One block per q-tile (512 blocks).
// Double-buffered LDS + next-chunk prefetch: one sync/iter, global-load
// latency hidden under accumulation.
// ---------------------------------------------------------------------------
__global__ __launch_bounds__(256) void merge_kernel(const u16* __restrict__ Opart,
                                                    const float* __restrict__ Mpart,
                                                    const float* __restrict__ Lpart,
                                                    float* __restrict__ out,
                                                    int SPLIT, int CT) {
    __shared__ float ld[2][64 * 33];
    const int tile = blockIdx.x;            // 0..511
    const int tid = threadIdx.x;
    const int q = tid >> 3, dg = tid & 7;
    const int qi = tile & 127;
    const int nkv = qi + 1;
    int nc = (nkv + CT - 1) / CT;
    if (nc > SPLIT) nc = SPLIT;

    float M = -3.0e38f;
    for (int c = 0; c < nc; ++c)
        M = fmaxf(M, Mpart[(tile * SPLIT + c) * 32 + q]);

    float L = 0.f;
    float acc[8];
#pragma unroll
    for (int j = 0; j < 8; ++j) acc[j] = 0.f;

    const int drow = tid >> 2;
    const int qq = (tid & 3) * 8;

    // prefetch chunk 0
    u16x8v v = reinterpret_cast<const u16x8v*>(Opart + (size_t)(tile * SPLIT) * 2048)[tid];

    for (int c = 0; c < nc; ++c) {
        const size_t base = (size_t)(tile * SPLIT + c);
        // stage current chunk into buffer c&1
        {
            float* dst = &ld[c & 1][drow * 33 + qq];
#pragma unroll
            for (int j = 0; j < 8; ++j) dst[j] = bf2f(v[j]);
        }
        // prefetch next chunk (clamped: last iter re-reads current, in-bounds)
        const int cn = (c + 1 < nc) ? c + 1 : c;
        v = reinterpret_cast<const u16x8v*>(Opart + (size_t)(tile * SPLIT + cn) * 2048)[tid];

        __syncthreads();
        float w = fexp2(Mpart[base * 32 + q] - M);
        L += w * Lpart[base * 32 + q];
        const float* src = &ld[c & 1][0];
#pragma unroll
        for (int j = 0; j < 8; ++j)
            acc[j] += w * src[(dg * 8 + j) * 33 + q];
        // no second barrier: next iter writes the OTHER buffer; the write of
        // THIS buffer two iters ahead is fenced by the next iteration's sync.
    }

    const float inv = 1.0f / L;
    float4 r0, r1;
    r0.x = acc[0] * inv; r0.y = acc[1] * inv; r0.z = acc[2] * inv; r0.w = acc[3] * inv;
    r1.x = acc[4] * inv; r1.y = acc[5] * inv; r1.z = acc[6] * inv; r1.w = acc[7] * inv;
    float4* dst = reinterpret_cast<float4*>(out + ((size_t)(tile * 32 + q)) * 64 + dg * 8);
    dst[0] = r0;
    dst[1] = r1;
}

// ---------------------------------------------------------------------------
extern "C" void kernel_launch(void* const* d_in, const int* in_sizes, int n_in,
                              void* d_out, int out_size, void* d_ws, size_t ws_size,
                              hipStream_t stream) {
    const float* x  = (const float*)d_in[0];
    const float* Wq = (const float*)d_in[1];
    const float* Wk = (const float*)d_in[2];
    const float* Wv = (const float*)d_in[3];
    float* out = (float*)d_out;

    char* ws = (char*)d_ws;
    const size_t MB = 1024 * 1024;
    u16* Qw  = (u16*)(ws);                     // 2 MiB
    u16* Kw  = (u16*)(ws + 2 * MB);            // 2 MiB
    u16* Vtw = (u16*)(ws + 4 * MB);            // 2 MiB
    u16* Wt  = (u16*)(ws + 6 * MB);            // 96 KiB

    int SPLIT = 16;
    while (SPLIT > 1) {
        size_t need = 8 * MB + (size_t)SPLIT * 2 * MB + (size_t)SPLIT * 128 * 1024;
        if (need <= ws_size) break;
        SPLIT >>= 1;
    }
    const int CT = (128 + SPLIT - 1) / SPLIT;

    u16* Opart = (u16*)(ws + 8 * MB);
    float* Mpart = (float*)(ws + 8 * MB + (size_t)SPLIT * 2 * MB);
    float* Lpart = Mpart + (size_t)SPLIT * 512 * 32;

    prep_kernel<<<384, 256, 0, stream>>>(Wq, Wk, Wv, Wt);
    proj_kernel<<<768, 256, 0, stream>>>(x, Wt, Qw, Kw, Vtw);
    attn_part_kernel<<<512 * SPLIT, 64, 0, stream>>>(Qw, Kw, Vtw, Opart, Mpart, Lpart,
                                                     SPLIT, CT);
    merge_kernel<<<512, 256, 0, stream>>>(Opart, Mpart, Lpart, out, SPLIT, CT);
}

// Round 11
// 94.876 us; speedup vs baseline: 1.1496x; 1.0601x over previous
//
#include <hip/hip_runtime.h>

#define DEV __device__ __forceinline__

typedef __bf16 bf16x8 __attribute__((ext_vector_type(8)));
typedef unsigned short u16x8v __attribute__((ext_vector_type(8)));
typedef float f32x4 __attribute__((ext_vector_type(4)));
typedef float f32x16 __attribute__((ext_vector_type(16)));
typedef unsigned int u32x4v __attribute__((ext_vector_type(4)));
typedef unsigned short u16;
typedef unsigned int u32;

// f32 -> bf16 bits, round-to-nearest-even (validated R1-R10, all signs)
DEV u16 f2bf(float f) {
    u32 u = __builtin_bit_cast(u32, f);
    u = (u + 0x7FFFu + ((u >> 16) & 1u)) >> 16;
    return (u16)u;
}

DEV float bf2f(u16 v) {
    return __builtin_bit_cast(float, (u32)v << 16);
}

DEV bf16x8 ld_bf8(const u16* p) {
    return *reinterpret_cast<const bf16x8*>(p);
}

// raw v_exp_f32 (validated R10)
DEV float fexp2(float x) { return __builtin_amdgcn_exp2f(x); }

// pack two f32 -> one u32 of 2 bf16 (lo=a, hi=b).  Validated ONLY for a,b>=0.
DEV u32 cvt_pk_bf16(float a, float b) {
    u32 r;
    asm("v_cvt_pk_bf16_f32 %0, %1, %2" : "=v"(r) : "v"(a), "v"(b));
    return r;
}

// chunk-table base offset: B(qi) = #chunks of tiles 0..qi-1 (CS=8)
DEV int chunk_base(int qi) {
    int g = qi >> 3, r = qi & 7;
    return qi + 4 * g * (g - 1) + r * g;
}

// ---------------------------------------------------------------------------
// Kernel 1: prep.  Blocks [0,384): weight transpose+convert (Wq pre-scaled by
// 1/sqrt(512)*log2(e)).  Blocks [384,392): build chunk table (1088 entries:
// qi | (k<<16) at index B(qi)+k for k=0..qi/8).
// ---------------------------------------------------------------------------
__global__ __launch_bounds__(256) void prep_kernel(const float* __restrict__ W0,
                                                   const float* __restrict__ W1,
                                                   const float* __restrict__ W2,
                                                   u16* __restrict__ Wt,
                                                   u32* __restrict__ table) {
    const int blk = blockIdx.x;
    if (blk < 384) {
        int idx = blk * 256 + threadIdx.x;   // 3*64*512 = 98304
        int w = idx >> 15, rem = idx & 32767, h = rem >> 9, c = rem & 511;
        const float* W = (w == 0) ? W0 : ((w == 1) ? W1 : W2);
        float v = W[c * 64 + h];
        if (w == 0) v *= 0.044194173824159216f * 1.4426950408889634f;  // SCL*log2e
        Wt[idx] = f2bf(v);
    } else {
        int idx = (blk - 384) * 256 + threadIdx.x;   // < 2048
        int qi = idx >> 4, k = idx & 15;
        if (k <= (qi >> 3))
            table[chunk_base(qi) + k] = (u32)qi | ((u32)k << 16);
    }
}

// ---------------------------------------------------------------------------
// Kernel 2: QKV projection, LDS-staged x.  256 blocks x 256 threads.
// Block owns 64 rows x all 3 mats (x read ONCE, coalesced 128B segments).
// Per kk: stage 64x32 f32->bf16 slab into LDS (row pitch 40 bf16,
// conflict-free), barrier, each wave ds_reads its A-frags, 12 MFMA.
// ---------------------------------------------------------------------------
__global__ __launch_bounds__(256) void proj_kernel(const float* __restrict__ x,
                                                   const u16* __restrict__ Wt,
                                                   u16* __restrict__ Q,
                                                   u16* __restrict__ Kq,
                                                   u16* __restrict__ Vt) {
    __shared__ __align__(16) u16 xs[64 * 40];
    const int tid = threadIdx.x;
    const int wave = tid >> 6, lane = tid & 63;
    const int lr = lane & 15, lg = lane >> 4;
    const int r0 = blockIdx.x * 64;
    const int srow = tid >> 3, scol = (tid & 7) * 4;   // staging coords (32 rows/pass)

    f32x4 acc[3][4];
#pragma unroll
    for (int m = 0; m < 3; ++m)
#pragma unroll
        for (int b = 0; b < 4; ++b) acc[m][b] = (f32x4){0.f, 0.f, 0.f, 0.f};

    for (int kk = 0; kk < 16; ++kk) {
        // stage: two passes of 32 rows; f32 -> bf16 during store
#pragma unroll
        for (int p = 0; p < 2; ++p) {
            const int row = p * 32 + srow;
            float4 a = *reinterpret_cast<const float4*>(
                x + (size_t)(r0 + row) * 512 + kk * 32 + scol);
            ushort4 hv;
            hv.x = f2bf(a.x); hv.y = f2bf(a.y); hv.z = f2bf(a.z); hv.w = f2bf(a.w);
            *reinterpret_cast<ushort4*>(&xs[row * 40 + scol]) = hv;
        }
        __syncthreads();

        bf16x8 af = ld_bf8(&xs[(wave * 16 + lr) * 40 + lg * 8]);
#pragma unroll
        for (int m = 0; m < 3; ++m) {
#pragma unroll
            for (int nt = 0; nt < 4; ++nt) {
                bf16x8 bf = ld_bf8(Wt + m * 32768 + (lr + 16 * nt) * 512 + kk * 32 + lg * 8);
                acc[m][nt] = __builtin_amdgcn_mfma_f32_16x16x32_bf16(af, bf, acc[m][nt], 0, 0, 0);
            }
        }
        __syncthreads();
    }

    const int rw = r0 + wave * 16;
    // Q, K row-major
#pragma unroll
    for (int nt = 0; nt < 4; ++nt) {
        const int h = lr + 16 * nt;
#pragma unroll
        for (int reg = 0; reg < 4; ++reg) {
            Q[(size_t)(rw + 4 * lg + reg) * 64 + h]  = f2bf(acc[0][nt][reg]);
            Kq[(size_t)(rw + 4 * lg + reg) * 64 + h] = f2bf(acc[1][nt][reg]);
        }
    }
    // V transposed: Vt[b][h][t]
    const int bidx = rw >> 12;
    const int t0 = (rw & 4095) + 4 * lg;
#pragma unroll
    for (int nt = 0; nt < 4; ++nt) {
        const int h = lr + 16 * nt;
        ushort4 hv;
        hv.x = f2bf(acc[2][nt][0]); hv.y = f2bf(acc[2][nt][1]);
        hv.z = f2bf(acc[2][nt][2]); hv.w = f2bf(acc[2][nt][3]);
        *reinterpret_cast<ushort4*>(Vt + ((size_t)(bidx * 64 + h)) * 4096 + t0) = hv;
    }
}

// ---------------------------------------------------------------------------
// Attention helpers (32x32 swapped-operand; validated R6-R10)
// ---------------------------------------------------------------------------
DEV f32x16 qk_sub(const u16* kp, const bf16x8 (&qf)[4]) {
    f32x16 st;
#pragma unroll
    for (int r = 0; r < 16; ++r) st[r] = 0.f;
#pragma unroll
    for (int kk = 0; kk < 4; ++kk)
        st = __builtin_amdgcn_mfma_f32_32x32x16_bf16(ld_bf8(kp + kk * 16), qf[kk], st, 0, 0, 0);
    return st;
}

DEV void mask_diag(f32x16& st, int q31, int hi) {
#pragma unroll
    for (int reg = 0; reg < 16; ++reg) {
        const int crow = (reg & 3) + 8 * (reg >> 2) + 4 * hi;
        if (crow > q31) st[reg] = -3.0e38f;
    }
}

DEV float max16(const f32x16& a) {
    float m0 = fmaxf(fmaxf(a[0], a[1]), a[2]);
    float m1 = fmaxf(fmaxf(a[3], a[4]), a[5]);
    float m2 = fmaxf(fmaxf(a[6], a[7]), a[8]);
    float m3 = fmaxf(fmaxf(a[9], a[10]), a[11]);
    float m4 = fmaxf(fmaxf(a[12], a[13]), a[14]);
    float m5 = fmaxf(fmaxf(m0, m1), a[15]);
    float m6 = fmaxf(fmaxf(m2, m3), m4);
    return fmaxf(m5, m6);
}

DEV float expsum(f32x16& st, float m) {
    float r0 = 0.f, r1 = 0.f, r2 = 0.f, r3 = 0.f;
#pragma unroll
    for (int g = 0; g < 4; ++g) {
        float p0 = fexp2(st[4 * g + 0] - m);
        float p1 = fexp2(st[4 * g + 1] - m);
        float p2 = fexp2(st[4 * g + 2] - m);
        float p3 = fexp2(st[4 * g + 3] - m);
        st[4 * g + 0] = p0; st[4 * g + 1] = p1;
        st[4 * g + 2] = p2; st[4 * g + 3] = p3;
        r0 += p0; r1 += p1; r2 += p2; r3 += p3;
    }
    return (r0 + r1) + (r2 + r3);
}

DEV void packP(const f32x16& st, bf16x8& pb0, bf16x8& pb1, int hi) {
    u32 A0 = cvt_pk_bf16(st[0], st[1]),  A1 = cvt_pk_bf16(st[2], st[3]);
    u32 A2 = cvt_pk_bf16(st[4], st[5]),  A3 = cvt_pk_bf16(st[6], st[7]);
    u32 A4 = cvt_pk_bf16(st[8], st[9]),  A5 = cvt_pk_bf16(st[10], st[11]);
    u32 A6 = cvt_pk_bf16(st[12], st[13]), A7 = cvt_pk_bf16(st[14], st[15]);
    u32 e0 = __shfl_xor(hi ? A0 : A2, 32, 64);
    u32 e1 = __shfl_xor(hi ? A1 : A3, 32, 64);
    u32 e2 = __shfl_xor(hi ? A4 : A6, 32, 64);
    u32 e3 = __shfl_xor(hi ? A5 : A7, 32, 64);
    u32x4v w0, w1;
    w0[0] = hi ? e0 : A0;
    w0[1] = hi ? e1 : A1;
    w0[2] = hi ? A2 : e0;
    w0[3] = hi ? A3 : e1;
    w1[0] = hi ? e2 : A4;
    w1[1] = hi ? e3 : A5;
    w1[2] = hi ? A6 : e2;
    w1[3] = hi ? A7 : e3;
    pb0 = __builtin_bit_cast(bf16x8, w0);
    pb1 = __builtin_bit_cast(bf16x8, w1);
}

DEV void pv(const u16* vp, const bf16x8& pb0, const bf16x8& pb1,
            f32x16& o0, f32x16& o1) {
    bf16x8 v00 = ld_bf8(vp);
    bf16x8 v01 = ld_bf8(vp + 16);
    bf16x8 v10 = ld_bf8(vp + 32 * 4096);
    bf16x8 v11 = ld_bf8(vp + 32 * 4096 + 16);
    o0 = __builtin_amdgcn_mfma_f32_32x32x16_bf16(v00, pb0, o0, 0, 0, 0);
    o0 = __builtin_amdgcn_mfma_f32_32x32x16_bf16(v01, pb1, o0, 0, 0, 0);
    o1 = __builtin_amdgcn_mfma_f32_32x32x16_bf16(v10, pb0, o1, 0, 0, 0);
    o1 = __builtin_amdgcn_mfma_f32_32x32x16_bf16(v11, pb1, o1, 0, 0, 0);
}

// ---------------------------------------------------------------------------
// Kernel 3: causal flash attention, swapped-operand 32x32, zero LDS,
// 1 wave/block, 2-ILP.  BALANCED LAUNCH: grid = 4 * 1088 chunks, every block
// active with <=8 subtiles (chunk table built in prep).  b = bid&3 spreads
// batches across XCDs; same-tile chunks adjacent for Q/L2 reuse.
// Partials bf16, fixed SPLIT=16 / CS=8 layout.
// ---------------------------------------------------------------------------
__global__ __launch_bounds__(64) void attn_part_kernel(const u16* __restrict__ Q,
                                                       const u16* __restrict__ K,
                                                       const u16* __restrict__ Vt,
                                                       const u32* __restrict__ table,
                                                       u16* __restrict__ Opart,
                                                       float* __restrict__ Mpart,
                                                       float* __restrict__ Lpart) {
    const int lane = threadIdx.x;
    const int q31 = lane & 31, hi = lane >> 5;
    const int bid = blockIdx.x;
    const int b = bid & 3;
    const u32 e = table[bid >> 2];
    const int qi = (int)(e & 0xffff);
    const int c = (int)(e >> 16);             // chunk index within tile
    const int qr0 = qi * 32;
    const int nkv = qi + 1;
    const int s0 = c * 8;
    const int s1 = min(nkv, s0 + 8);
    const int tile = (b << 7) | qi;

    const u16* Qb = Q + (size_t)b * 4096 * 64;
    const u16* Kb = K + (size_t)b * 4096 * 64;
    const u16* Vb = Vt + (size_t)b * 64 * 4096;

    bf16x8 qf[4];
#pragma unroll
    for (int kk = 0; kk < 4; ++kk)
        qf[kk] = ld_bf8(Qb + (size_t)(qr0 + q31) * 64 + kk * 16 + hi * 8);

    f32x16 o0, o1;
#pragma unroll
    for (int r = 0; r < 16; ++r) { o0[r] = 0.f; o1[r] = 0.f; }
    float m_run = -1.0e30f, l_run = 0.f;

    for (int s = s0; s < s1; s += 2) {
        const int kv0 = s * 32;
        const bool hasB = (s + 1 < s1);
        const u16* kpA = Kb + (size_t)(kv0 + q31) * 64 + hi * 8;

        f32x16 stA = qk_sub(kpA, qf);
        f32x16 stB;
        if (hasB) stB = qk_sub(kpA + 2048, qf);

        if (s == qi) mask_diag(stA, q31, hi);
        if (hasB && s + 1 == qi) mask_diag(stB, q31, hi);

        float pm = hasB ? fmaxf(max16(stA), max16(stB)) : max16(stA);
        pm = fmaxf(pm, __shfl_xor(pm, 32, 64));

        // defer-rescale (THR = 11.5 log2-units)
        if (!__all(pm - m_run <= 11.5f)) {
            float mn = fmaxf(m_run, pm);
            float al = fexp2(m_run - mn);
            m_run = mn;
            l_run *= al;
#pragma unroll
            for (int r = 0; r < 16; ++r) { o0[r] *= al; o1[r] *= al; }
        }

        float rs = expsum(stA, m_run);
        if (hasB) rs += expsum(stB, m_run);
        rs += __shfl_xor(rs, 32, 64);
        l_run += rs;

        const u16* vp = Vb + (size_t)q31 * 4096 + kv0 + hi * 8;
        bf16x8 p0, p1;
        packP(stA, p0, p1, hi);
        pv(vp, p0, p1, o0, o1);
        if (hasB) {
            packP(stB, p0, p1, hi);
            pv(vp + 32, p0, p1, o0, o1);
        }
    }

    // write transposed partials (bf16): Opart[tile*16+c][d][q]
    const size_t base = (size_t)(tile * 16 + c);
    u16* Op = Opart + base * 2048;
#pragma unroll
    for (int reg = 0; reg < 16; ++reg) {
        const int crow = (reg & 3) + 8 * (reg >> 2) + 4 * hi;
        Op[crow * 32 + q31] = f2bf(o0[reg]);
        Op[(32 + crow) * 32 + q31] = f2bf(o1[reg]);
    }
    if (lane < 32) {
        Mpart[base * 32 + lane] = m_run;
        Lpart[base * 32 + lane] = l_run;
    }
}

// ---------------------------------------------------------------------------
// Kernel 4: merge partials (bf16 Opart).  One block per q-tile (512 blocks).
// Double-buffered LDS + next-chunk prefetch (validated R10).
// ---------------------------------------------------------------------------
__global__ __launch_bounds__(256) void merge_kernel(const u16* __restrict__ Opart,
                                                    const float* __restrict__ Mpart,
                                                    const float* __restrict__ Lpart,
                                                    float* __restrict__ out) {
    __shared__ float ld[2][64 * 33];
    const int tile = blockIdx.x;            // 0..511
    const int tid = threadIdx.x;
    const int q = tid >> 3, dg = tid & 7;
    const int qi = tile & 127;
    const int nkv = qi + 1;
    const int nc = (nkv + 7) >> 3;          // = chunks for this tile, <= 16

    float M = -3.0e38f;
    for (int c = 0; c < nc; ++c)
        M = fmaxf(M, Mpart[(tile * 16 + c) * 32 + q]);

    float L = 0.f;
    float acc[8];
#pragma unroll
    for (int j = 0; j < 8; ++j) acc[j] = 0.f;

    const int drow = tid >> 2;
    const int qq = (tid & 3) * 8;

    u16x8v v = reinterpret_cast<const u16x8v*>(Opart + (size_t)(tile * 16) * 2048)[tid];

    for (int c = 0; c < nc; ++c) {
        const size_t base = (size_t)(tile * 16 + c);
        {
            float* dst = &ld[c & 1][drow * 33 + qq];
#pragma unroll
            for (int j = 0; j < 8; ++j) dst[j] = bf2f(v[j]);
        }
        const int cn = (c + 1 < nc) ? c + 1 : c;
        v = reinterpret_cast<const u16x8v*>(Opart + (size_t)(tile * 16 + cn) * 2048)[tid];

        __syncthreads();
        float w = fexp2(Mpart[base * 32 + q] - M);
        L += w * Lpart[base * 32 + q];
        const float* src = &ld[c & 1][0];
#pragma unroll
        for (int j = 0; j < 8; ++j)
            acc[j] += w * src[(dg * 8 + j) * 33 + q];
    }

    const float inv = 1.0f / L;
    float4 r0, r1;
    r0.x = acc[0] * inv; r0.y = acc[1] * inv; r0.z = acc[2] * inv; r0.w = acc[3] * inv;
    r1.x = acc[4] * inv; r1.y = acc[5] * inv; r1.z = acc[6] * inv; r1.w = acc[7] * inv;
    float4* dst = reinterpret_cast<float4*>(out + ((size_t)(tile * 32 + q)) * 64 + dg * 8);
    dst[0] = r0;
    dst[1] = r1;
}

// ---------------------------------------------------------------------------
extern "C" void kernel_launch(void* const* d_in, const int* in_sizes, int n_in,
                              void* d_out, int out_size, void* d_ws, size_t ws_size,
                              hipStream_t stream) {
    const float* x  = (const float*)d_in[0];
    const float* Wq = (const float*)d_in[1];
    const float* Wk = (const float*)d_in[2];
    const float* Wv = (const float*)d_in[3];
    float* out = (float*)d_out;

    char* ws = (char*)d_ws;
    const size_t MB = 1024 * 1024;
    u16* Qw  = (u16*)(ws);                     // 2 MiB
    u16* Kw  = (u16*)(ws + 2 * MB);            // 2 MiB
    u16* Vtw = (u16*)(ws + 4 * MB);            // 2 MiB
    u16* Wt  = (u16*)(ws + 6 * MB);            // 192 KiB used of 2 MiB slack
    u32* table = (u32*)(ws + 7 * MB);          // 4.25 KiB

    // Opart bf16: 16 chunks * 512 tiles * 4KB = 32 MiB; M/L: 512KB each region
    u16* Opart = (u16*)(ws + 8 * MB);
    float* Mpart = (float*)(ws + 8 * MB + 32 * MB);
    float* Lpart = Mpart + (size_t)16 * 512 * 32;

    prep_kernel<<<392, 256, 0, stream>>>(Wq, Wk, Wv, Wt, table);
    proj_kernel<<<256, 256, 0, stream>>>(x, Wt, Qw, Kw, Vtw);
    attn_part_kernel<<<4 * 1088, 64, 0, stream>>>(Qw, Kw, Vtw, table, Opart, Mpart, Lpart);
    merge_kernel<<<512, 256, 0, stream>>>(Opart, Mpart, Lpart, out);
}

// Round 13
// 92.700 us; speedup vs baseline: 1.1765x; 1.0235x over previous
//
#include <hip/hip_runtime.h>

#define DEV __device__ __forceinline__

typedef __bf16 bf16x8 __attribute__((ext_vector_type(8)));
typedef unsigned short u16x8v __attribute__((ext_vector_type(8)));
typedef float f32x4 __attribute__((ext_vector_type(4)));
typedef float f32x16 __attribute__((ext_vector_type(16)));
typedef unsigned int u32x4v __attribute__((ext_vector_type(4)));
typedef unsigned short u16;
typedef unsigned int u32;

// f32 -> bf16 bits, round-to-nearest-even (validated R1-R11, all signs)
DEV u16 f2bf(float f) {
    u32 u = __builtin_bit_cast(u32, f);
    u = (u + 0x7FFFu + ((u >> 16) & 1u)) >> 16;
    return (u16)u;
}

DEV float bf2f(u16 v) {
    return __builtin_bit_cast(float, (u32)v << 16);
}

DEV bf16x8 ld_bf8(const u16* p) {
    return *reinterpret_cast<const bf16x8*>(p);
}

// raw v_exp_f32 (validated R10)
DEV float fexp2(float x) { return __builtin_amdgcn_exp2f(x); }

// pack two f32 -> one u32 of 2 bf16 (lo=a, hi=b).  Validated ONLY for a,b>=0.
DEV u32 cvt_pk_bf16(float a, float b) {
    u32 r;
    asm("v_cvt_pk_bf16_f32 %0, %1, %2" : "=v"(r) : "v"(a), "v"(b));
    return r;
}

// NOTE: v_permlane32_swap_b32 is BANNED here.  Two uses (R5 packP, R12
// cross-half reduce) both failed with absmax 0.71; even the "direction-proof"
// a==b form is empirically wrong vs my model.  __shfl_xor is validated.

// chunk-table base offset: B(qi) = #chunks of tiles 0..qi-1 (CS=8)
DEV int chunk_base(int qi) {
    int g = qi >> 3, r = qi & 7;
    return qi + 4 * g * (g - 1) + r * g;
}

// ---------------------------------------------------------------------------
// Kernel 1: prep.  Blocks [0,384): weight transpose+convert (Wq pre-scaled by
// 1/sqrt(512)*log2(e)).  Blocks [384,392): build chunk table (1088 entries).
// ---------------------------------------------------------------------------
__global__ __launch_bounds__(256) void prep_kernel(const float* __restrict__ W0,
                                                   const float* __restrict__ W1,
                                                   const float* __restrict__ W2,
                                                   u16* __restrict__ Wt,
                                                   u32* __restrict__ table) {
    const int blk = blockIdx.x;
    if (blk < 384) {
        int idx = blk * 256 + threadIdx.x;   // 3*64*512 = 98304
        int w = idx >> 15, rem = idx & 32767, h = rem >> 9, c = rem & 511;
        const float* W = (w == 0) ? W0 : ((w == 1) ? W1 : W2);
        float v = W[c * 64 + h];
        if (w == 0) v *= 0.044194173824159216f * 1.4426950408889634f;  // SCL*log2e
        Wt[idx] = f2bf(v);
    } else {
        int idx = (blk - 384) * 256 + threadIdx.x;   // < 2048
        int qi = idx >> 4, k = idx & 15;
        if (k <= (qi >> 3))
            table[chunk_base(qi) + k] = (u32)qi | ((u32)k << 16);
    }
}

// ---------------------------------------------------------------------------
// Kernel 2: QKV projection, LDS-staged x (validated R11).
// ---------------------------------------------------------------------------
__global__ __launch_bounds__(256) void proj_kernel(const float* __restrict__ x,
                                                   const u16* __restrict__ Wt,
                                                   u16* __restrict__ Q,
                                                   u16* __restrict__ Kq,
                                                   u16* __restrict__ Vt) {
    __shared__ __align__(16) u16 xs[64 * 40];
    const int tid = threadIdx.x;
    const int wave = tid >> 6, lane = tid & 63;
    const int lr = lane & 15, lg = lane >> 4;
    const int r0 = blockIdx.x * 64;
    const int srow = tid >> 3, scol = (tid & 7) * 4;

    f32x4 acc[3][4];
#pragma unroll
    for (int m = 0; m < 3; ++m)
#pragma unroll
        for (int b = 0; b < 4; ++b) acc[m][b] = (f32x4){0.f, 0.f, 0.f, 0.f};

    for (int kk = 0; kk < 16; ++kk) {
#pragma unroll
        for (int p = 0; p < 2; ++p) {
            const int row = p * 32 + srow;
            float4 a = *reinterpret_cast<const float4*>(
                x + (size_t)(r0 + row) * 512 + kk * 32 + scol);
            ushort4 hv;
            hv.x = f2bf(a.x); hv.y = f2bf(a.y); hv.z = f2bf(a.z); hv.w = f2bf(a.w);
            *reinterpret_cast<ushort4*>(&xs[row * 40 + scol]) = hv;
        }
        __syncthreads();

        bf16x8 af = ld_bf8(&xs[(wave * 16 + lr) * 40 + lg * 8]);
#pragma unroll
        for (int m = 0; m < 3; ++m) {
#pragma unroll
            for (int nt = 0; nt < 4; ++nt) {
                bf16x8 bf = ld_bf8(Wt + m * 32768 + (lr + 16 * nt) * 512 + kk * 32 + lg * 8);
                acc[m][nt] = __builtin_amdgcn_mfma_f32_16x16x32_bf16(af, bf, acc[m][nt], 0, 0, 0);
            }
        }
        __syncthreads();
    }

    const int rw = r0 + wave * 16;
#pragma unroll
    for (int nt = 0; nt < 4; ++nt) {
        const int h = lr + 16 * nt;
#pragma unroll
        for (int reg = 0; reg < 4; ++reg) {
            Q[(size_t)(rw + 4 * lg + reg) * 64 + h]  = f2bf(acc[0][nt][reg]);
            Kq[(size_t)(rw + 4 * lg + reg) * 64 + h] = f2bf(acc[1][nt][reg]);
        }
    }
    const int bidx = rw >> 12;
    const int t0 = (rw & 4095) + 4 * lg;
#pragma unroll
    for (int nt = 0; nt < 4; ++nt) {
        const int h = lr + 16 * nt;
        ushort4 hv;
        hv.x = f2bf(acc[2][nt][0]); hv.y = f2bf(acc[2][nt][1]);
        hv.z = f2bf(acc[2][nt][2]); hv.w = f2bf(acc[2][nt][3]);
        *reinterpret_cast<ushort4*>(Vt + ((size_t)(bidx * 64 + h)) * 4096 + t0) = hv;
    }
}

// ---------------------------------------------------------------------------
// Attention helpers (32x32 swapped-operand; validated R6-R11)
// ---------------------------------------------------------------------------
DEV void mask_diag(f32x16& st, int q31, int hi) {
#pragma unroll
    for (int reg = 0; reg < 16; ++reg) {
        const int crow = (reg & 3) + 8 * (reg >> 2) + 4 * hi;
        if (crow > q31) st[reg] = -3.0e38f;
    }
}

DEV float max16(const f32x16& a) {
    float m0 = fmaxf(fmaxf(a[0], a[1]), a[2]);
    float m1 = fmaxf(fmaxf(a[3], a[4]), a[5]);
    float m2 = fmaxf(fmaxf(a[6], a[7]), a[8]);
    float m3 = fmaxf(fmaxf(a[9], a[10]), a[11]);
    float m4 = fmaxf(fmaxf(a[12], a[13]), a[14]);
    float m5 = fmaxf(fmaxf(m0, m1), a[15]);
    float m6 = fmaxf(fmaxf(m2, m3), m4);
    return fmaxf(m5, m6);
}

DEV float expsum(f32x16& st, float m) {
    float r0 = 0.f, r1 = 0.f, r2 = 0.f, r3 = 0.f;
#pragma unroll
    for (int g = 0; g < 4; ++g) {
        float p0 = fexp2(st[4 * g + 0] - m);
        float p1 = fexp2(st[4 * g + 1] - m);
        float p2 = fexp2(st[4 * g + 2] - m);
        float p3 = fexp2(st[4 * g + 3] - m);
        st[4 * g + 0] = p0; st[4 * g + 1] = p1;
        st[4 * g + 2] = p2; st[4 * g + 3] = p3;
        r0 += p0; r1 += p1; r2 += p2; r3 += p3;
    }
    return (r0 + r1) + (r2 + r3);
}

DEV void packP(const f32x16& st, bf16x8& pb0, bf16x8& pb1, int hi) {
    u32 A0 = cvt_pk_bf16(st[0], st[1]),  A1 = cvt_pk_bf16(st[2], st[3]);
    u32 A2 = cvt_pk_bf16(st[4], st[5]),  A3 = cvt_pk_bf16(st[6], st[7]);
    u32 A4 = cvt_pk_bf16(st[8], st[9]),  A5 = cvt_pk_bf16(st[10], st[11]);
    u32 A6 = cvt_pk_bf16(st[12], st[13]), A7 = cvt_pk_bf16(st[14], st[15]);
    u32 e0 = __shfl_xor(hi ? A0 : A2, 32, 64);
    u32 e1 = __shfl_xor(hi ? A1 : A3, 32, 64);
    u32 e2 = __shfl_xor(hi ? A4 : A6, 32, 64);
    u32 e3 = __shfl_xor(hi ? A5 : A7, 32, 64);
    u32x4v w0, w1;
    w0[0] = hi ? e0 : A0;
    w0[1] = hi ? e1 : A1;
    w0[2] = hi ? A2 : e0;
    w0[3] = hi ? A3 : e1;
    w1[0] = hi ? e2 : A4;
    w1[1] = hi ? e3 : A5;
    w1[2] = hi ? A6 : e2;
    w1[3] = hi ? A7 : e3;
    pb0 = __builtin_bit_cast(bf16x8, w0);
    pb1 = __builtin_bit_cast(bf16x8, w1);
}

DEV void pv(const u16* vp, const bf16x8& pb0, const bf16x8& pb1,
            f32x16& o0, f32x16& o1) {
    bf16x8 v00 = ld_bf8(vp);
    bf16x8 v01 = ld_bf8(vp + 16);
    bf16x8 v10 = ld_bf8(vp + 32 * 4096);
    bf16x8 v11 = ld_bf8(vp + 32 * 4096 + 16);
    o0 = __builtin_amdgcn_mfma_f32_32x32x16_bf16(v00, pb0, o0, 0, 0, 0);
    o0 = __builtin_amdgcn_mfma_f32_32x32x16_bf16(v01, pb1, o0, 0, 0, 0);
    o1 = __builtin_amdgcn_mfma_f32_32x32x16_bf16(v10, pb0, o1, 0, 0, 0);
    o1 = __builtin_amdgcn_mfma_f32_32x32x16_bf16(v11, pb1, o1, 0, 0, 0);
}

// issue K loads for the subtile pair starting at s (clamped to < s1)
DEV void loadK(bf16x8 (&kb)[8], const u16* Kb, int s, int s1, int q31, int hi) {
    const int sA = s;
    const int sB = (s + 1 < s1) ? s + 1 : s;
    const u16* pA = Kb + (size_t)(sA * 32 + q31) * 64 + hi * 8;
    const u16* pB = Kb + (size_t)(sB * 32 + q31) * 64 + hi * 8;
#pragma unroll
    for (int kk = 0; kk < 4; ++kk) {
        kb[kk] = ld_bf8(pA + kk * 16);
        kb[4 + kk] = ld_bf8(pB + kk * 16);
    }
}

// ---------------------------------------------------------------------------
// One subtile-pair step using prefetched K fragments.
// ---------------------------------------------------------------------------
DEV void attn_pair(const bf16x8 (&kc)[8], const bf16x8 (&qf)[4],
                   const u16* Vb, int s, int s1, int qi, int q31, int hi,
                   f32x16& o0, f32x16& o1, float& m_run, float& l_run) {
    const int kv0 = s * 32;
    const bool hasB = (s + 1 < s1);

    f32x16 stA, stB;
#pragma unroll
    for (int r = 0; r < 16; ++r) stA[r] = 0.f;
#pragma unroll
    for (int kk = 0; kk < 4; ++kk)
        stA = __builtin_amdgcn_mfma_f32_32x32x16_bf16(kc[kk], qf[kk], stA, 0, 0, 0);
    if (hasB) {
#pragma unroll
        for (int r = 0; r < 16; ++r) stB[r] = 0.f;
#pragma unroll
        for (int kk = 0; kk < 4; ++kk)
            stB = __builtin_amdgcn_mfma_f32_32x32x16_bf16(kc[4 + kk], qf[kk], stB, 0, 0, 0);
    }

    if (s == qi) mask_diag(stA, q31, hi);
    if (hasB && s + 1 == qi) mask_diag(stB, q31, hi);

    float pm = hasB ? fmaxf(max16(stA), max16(stB)) : max16(stA);
    pm = fmaxf(pm, __shfl_xor(pm, 32, 64));

    // defer-rescale (THR = 11.5 log2-units)
    if (!__all(pm - m_run <= 11.5f)) {
        float mn = fmaxf(m_run, pm);
        float al = fexp2(m_run - mn);
        m_run = mn;
        l_run *= al;
#pragma unroll
        for (int r = 0; r < 16; ++r) { o0[r] *= al; o1[r] *= al; }
    }

    float rs = expsum(stA, m_run);
    if (hasB) rs += expsum(stB, m_run);
    rs += __shfl_xor(rs, 32, 64);
    l_run += rs;

    const u16* vp = Vb + (size_t)q31 * 4096 + kv0 + hi * 8;
    bf16x8 p0, p1;
    packP(stA, p0, p1, hi);
    pv(vp, p0, p1, o0, o1);
    if (hasB) {
        packP(stB, p0, p1, hi);
        pv(vp + 32, p0, p1, o0, o1);
    }
}

// ---------------------------------------------------------------------------
// Kernel 3: causal flash attention, swapped-operand 32x32, zero LDS,
// 1 wave/block, 2-ILP, balanced chunk-table launch (R11), plus
// cross-iteration K prefetch (ping-pong ka/kb).  All cross-lane ops are
// validated __shfl_xor.  Partials bf16, SPLIT=16/CS=8 layout.
// ---------------------------------------------------------------------------
__global__ __launch_bounds__(64) void attn_part_kernel(const u16* __restrict__ Q,
                                                       const u16* __restrict__ K,
                                                       const u16* __restrict__ Vt,
                                                       const u32* __restrict__ table,
                                                       u16* __restrict__ Opart,
                                                       float* __restrict__ Mpart,
                                                       float* __restrict__ Lpart) {
    const int lane = threadIdx.x;
    const int q31 = lane & 31, hi = lane >> 5;
    const int bid = blockIdx.x;
    const int b = bid & 3;
    const u32 e = table[bid >> 2];
    const int qi = (int)(e & 0xffff);
    const int c = (int)(e >> 16);
    const int qr0 = qi * 32;
    const int nkv = qi + 1;
    const int s0 = c * 8;
    const int s1 = min(nkv, s0 + 8);
    const int tile = (b << 7) | qi;

    const u16* Qb = Q + (size_t)b * 4096 * 64;
    const u16* Kb = K + (size_t)b * 4096 * 64;
    const u16* Vb = Vt + (size_t)b * 64 * 4096;

    bf16x8 qf[4];
#pragma unroll
    for (int kk = 0; kk < 4; ++kk)
        qf[kk] = ld_bf8(Qb + (size_t)(qr0 + q31) * 64 + kk * 16 + hi * 8);

    f32x16 o0, o1;
#pragma unroll
    for (int r = 0; r < 16; ++r) { o0[r] = 0.f; o1[r] = 0.f; }
    float m_run = -1.0e30f, l_run = 0.f;

    bf16x8 ka[8], kb[8];
    loadK(ka, Kb, s0, s1, q31, hi);

    int s = s0;
    while (true) {
        int nxt = s + 2;
        if (nxt < s1) loadK(kb, Kb, nxt, s1, q31, hi);   // issue before compute
        attn_pair(ka, qf, Vb, s, s1, qi, q31, hi, o0, o1, m_run, l_run);
        s = nxt;
        if (s >= s1) break;

        nxt = s + 2;
        if (nxt < s1) loadK(ka, Kb, nxt, s1, q31, hi);
        attn_pair(kb, qf, Vb, s, s1, qi, q31, hi, o0, o1, m_run, l_run);
        s = nxt;
        if (s >= s1) break;
    }

    // write transposed partials (bf16): Opart[tile*16+c][d][q]
    const size_t base = (size_t)(tile * 16 + c);
    u16* Op = Opart + base * 2048;
#pragma unroll
    for (int reg = 0; reg < 16; ++reg) {
        const int crow = (reg & 3) + 8 * (reg >> 2) + 4 * hi;
        Op[crow * 32 + q31] = f2bf(o0[reg]);
        Op[(32 + crow) * 32 + q31] = f2bf(o1[reg]);
    }
    if (lane < 32) {
        Mpart[base * 32 + lane] = m_run;
        Lpart[base * 32 + lane] = l_run;
    }
}

// ---------------------------------------------------------------------------
// Kernel 4: merge partials (bf16 Opart).  One block per q-tile (512 blocks).
// Double-buffered LDS + next-chunk prefetch (validated R10/R11).
// ---------------------------------------------------------------------------
__global__ __launch_bounds__(256) void merge_kernel(const u16* __restrict__ Opart,
                                                    const float* __restrict__ Mpart,
                                                    const float* __restrict__ Lpart,
                                                    float* __restrict__ out) {
    __shared__ float ld[2][64 * 33];
    const int tile = blockIdx.x;            // 0..511
    const int tid = threadIdx.x;
    const int q = tid >> 3, dg = tid & 7;
    const int qi = tile & 127;
    const int nkv = qi + 1;
    const int nc = (nkv + 7) >> 3;

    float M = -3.0e38f;
    for (int c = 0; c < nc; ++c)
        M = fmaxf(M, Mpart[(tile * 16 + c) * 32 + q]);

    float L = 0.f;
    float acc[8];
#pragma unroll
    for (int j = 0; j < 8; ++j) acc[j] = 0.f;

    const int drow = tid >> 2;
    const int qq = (tid & 3) * 8;

    u16x8v v = reinterpret_cast<const u16x8v*>(Opart + (size_t)(tile * 16) * 2048)[tid];

    for (int c = 0; c < nc; ++c) {
        const size_t base = (size_t)(tile * 16 + c);
        {
            float* dst = &ld[c & 1][drow * 33 + qq];
#pragma unroll
            for (int j = 0; j < 8; ++j) dst[j] = bf2f(v[j]);
        }
        const int cn = (c + 1 < nc) ? c + 1 : c;
        v = reinterpret_cast<const u16x8v*>(Opart + (size_t)(tile * 16 + cn) * 2048)[tid];

        __syncthreads();
        float w = fexp2(Mpart[base * 32 + q] - M);
        L += w * Lpart[base * 32 + q];
        const float* src = &ld[c & 1][0];
#pragma unroll
        for (int j = 0; j < 8; ++j)
            acc[j] += w * src[(dg * 8 + j) * 33 + q];
    }

    const float inv = 1.0f / L;
    float4 r0, r1;
    r0.x = acc[0] * inv; r0.y = acc[1] * inv; r0.z = acc[2] * inv; r0.w = acc[3] * inv;
    r1.x = acc[4] * inv; r1.y = acc[5] * inv; r1.z = acc[6] * inv; r1.w = acc[7] * inv;
    float4* dst = reinterpret_cast<float4*>(out + ((size_t)(tile * 32 + q)) * 64 + dg * 8);
    dst[0] = r0;
    dst[1] = r1;
}

// ---------------------------------------------------------------------------
extern "C" void kernel_launch(void* const* d_in, const int* in_sizes, int n_in,
                              void* d_out, int out_size, void* d_ws, size_t ws_size,
                              hipStream_t stream) {
    const float* x  = (const float*)d_in[0];
    const float* Wq = (const float*)d_in[1];
    const float* Wk = (const float*)d_in[2];
    const float* Wv = (const float*)d_in[3];
    float* out = (float*)d_out;

    char* ws = (char*)d_ws;
    const size_t MB = 1024 * 1024;
    u16* Qw  = (u16*)(ws);                     // 2 MiB
    u16* Kw  = (u16*)(ws + 2 * MB);            // 2 MiB
    u16* Vtw = (u16*)(ws + 4 * MB);            // 2 MiB
    u16* Wt  = (u16*)(ws + 6 * MB);            // 192 KiB
    u32* table = (u32*)(ws + 7 * MB);          // 4.25 KiB

    u16* Opart = (u16*)(ws + 8 * MB);          // 32 MiB
    float* Mpart = (float*)(ws + 8 * MB + 32 * MB);
    float* Lpart = Mpart + (size_t)16 * 512 * 32;

    prep_kernel<<<392, 256, 0, stream>>>(Wq, Wk, Wv, Wt, table);
    proj_kernel<<<256, 256, 0, stream>>>(x, Wt, Qw, Kw, Vtw);
    attn_part_kernel<<<4 * 1088, 64, 0, stream>>>(Qw, Kw, Vtw, table, Opart, Mpart, Lpart);
    merge_kernel<<<512, 256, 0, stream>>>(Opart, Mpart, Lpart, out);
}

// Round 14
// 74.961 us; speedup vs baseline: 1.4550x; 1.2367x over previous
//
#include <hip/hip_runtime.h>

#define DEV __device__ __forceinline__

typedef __bf16 bf16x8 __attribute__((ext_vector_type(8)));
typedef unsigned short u16x8v __attribute__((ext_vector_type(8)));
typedef float f32x4 __attribute__((ext_vector_type(4)));
typedef float f32x16 __attribute__((ext_vector_type(16)));
typedef unsigned int u32x4v __attribute__((ext_vector_type(4)));
typedef unsigned short u16;
typedef unsigned int u32;

// f32 -> bf16 bits, round-to-nearest-even (validated R1-R13, all signs)
DEV u16 f2bf(float f) {
    u32 u = __builtin_bit_cast(u32, f);
    u = (u + 0x7FFFu + ((u >> 16) & 1u)) >> 16;
    return (u16)u;
}

DEV float bf2f(u16 v) {
    return __builtin_bit_cast(float, (u32)v << 16);
}

DEV bf16x8 ld_bf8(const u16* p) {
    return *reinterpret_cast<const bf16x8*>(p);
}

// 8B-alignment-safe 16B read (LDS rows padded to 8B multiples, not 16B)
DEV bf16x8 ld_lds8(const u16* p) {
    ushort4 a = *reinterpret_cast<const ushort4*>(p);
    ushort4 b = *reinterpret_cast<const ushort4*>(p + 4);
    u16x8v o;
    o[0] = a.x; o[1] = a.y; o[2] = a.z; o[3] = a.w;
    o[4] = b.x; o[5] = b.y; o[6] = b.z; o[7] = b.w;
    return __builtin_bit_cast(bf16x8, o);
}

// raw v_exp_f32 (validated R10)
DEV float fexp2(float x) { return __builtin_amdgcn_exp2f(x); }

// pack two f32 -> one u32 of 2 bf16 (lo=a, hi=b).  Validated ONLY for a,b>=0.
DEV u32 cvt_pk_bf16(float a, float b) {
    u32 r;
    asm("v_cvt_pk_bf16_f32 %0, %1, %2" : "=v"(r) : "v"(a), "v"(b));
    return r;
}

// NOTE: v_permlane32_swap_b32 is BANNED (R5, R12 both failed absmax 0.71).

// base offset of q-block j in the 272-entry chunk table:
// B(j) = sum_{i<j} (floor(i/2)+1) = j + g*(g-1) + r*g,  g=j>>1, r=j&1
DEV int block_base(int j) {
    int g = j >> 1, r = j & 1;
    return j + g * (g - 1) + r * g;
}

// ---------------------------------------------------------------------------
// Kernel 1: prep.  Blocks [0,384): weight transpose+convert (Wq pre-scaled by
// 1/sqrt(512)*log2(e)).  Blocks [384,386): build 272-entry chunk table:
// entry (j | c<<16) at block_base(j)+c for c=0..j/2.
// ---------------------------------------------------------------------------
__global__ __launch_bounds__(256) void prep_kernel(const float* __restrict__ W0,
                                                   const float* __restrict__ W1,
                                                   const float* __restrict__ W2,
                                                   u16* __restrict__ Wt,
                                                   u32* __restrict__ table) {
    const int blk = blockIdx.x;
    if (blk < 384) {
        int idx = blk * 256 + threadIdx.x;   // 3*64*512 = 98304
        int w = idx >> 15, rem = idx & 32767, h = rem >> 9, c = rem & 511;
        const float* W = (w == 0) ? W0 : ((w == 1) ? W1 : W2);
        float v = W[c * 64 + h];
        if (w == 0) v *= 0.044194173824159216f * 1.4426950408889634f;  // SCL*log2e
        Wt[idx] = f2bf(v);
    } else {
        int idx = (blk - 384) * 256 + threadIdx.x;   // < 512
        if (idx < 512) {
            int j = idx >> 4, k = idx & 15;
            if (k <= (j >> 1))
                table[block_base(j) + k] = (u32)j | ((u32)k << 16);
        }
    }
}

// ---------------------------------------------------------------------------
// Kernel 2: QKV projection, LDS-staged x (validated R11).
// ---------------------------------------------------------------------------
__global__ __launch_bounds__(256) void proj_kernel(const float* __restrict__ x,
                                                   const u16* __restrict__ Wt,
                                                   u16* __restrict__ Q,
                                                   u16* __restrict__ Kq,
                                                   u16* __restrict__ Vt) {
    __shared__ __align__(16) u16 xs[64 * 40];
    const int tid = threadIdx.x;
    const int wave = tid >> 6, lane = tid & 63;
    const int lr = lane & 15, lg = lane >> 4;
    const int r0 = blockIdx.x * 64;
    const int srow = tid >> 3, scol = (tid & 7) * 4;

    f32x4 acc[3][4];
#pragma unroll
    for (int m = 0; m < 3; ++m)
#pragma unroll
        for (int b = 0; b < 4; ++b) acc[m][b] = (f32x4){0.f, 0.f, 0.f, 0.f};

    for (int kk = 0; kk < 16; ++kk) {
#pragma unroll
        for (int p = 0; p < 2; ++p) {
            const int row = p * 32 + srow;
            float4 a = *reinterpret_cast<const float4*>(
                x + (size_t)(r0 + row) * 512 + kk * 32 + scol);
            ushort4 hv;
            hv.x = f2bf(a.x); hv.y = f2bf(a.y); hv.z = f2bf(a.z); hv.w = f2bf(a.w);
            *reinterpret_cast<ushort4*>(&xs[row * 40 + scol]) = hv;
        }
        __syncthreads();

        bf16x8 af = ld_bf8(&xs[(wave * 16 + lr) * 40 + lg * 8]);
#pragma unroll
        for (int m = 0; m < 3; ++m) {
#pragma unroll
            for (int nt = 0; nt < 4; ++nt) {
                bf16x8 bf = ld_bf8(Wt + m * 32768 + (lr + 16 * nt) * 512 + kk * 32 + lg * 8);
                acc[m][nt] = __builtin_amdgcn_mfma_f32_16x16x32_bf16(af, bf, acc[m][nt], 0, 0, 0);
            }
        }
        __syncthreads();
    }

    const int rw = r0 + wave * 16;
#pragma unroll
    for (int nt = 0; nt < 4; ++nt) {
        const int h = lr + 16 * nt;
#pragma unroll
        for (int reg = 0; reg < 4; ++reg) {
            Q[(size_t)(rw + 4 * lg + reg) * 64 + h]  = f2bf(acc[0][nt][reg]);
            Kq[(size_t)(rw + 4 * lg + reg) * 64 + h] = f2bf(acc[1][nt][reg]);
        }
    }
    const int bidx = rw >> 12;
    const int t0 = (rw & 4095) + 4 * lg;
#pragma unroll
    for (int nt = 0; nt < 4; ++nt) {
        const int h = lr + 16 * nt;
        ushort4 hv;
        hv.x = f2bf(acc[2][nt][0]); hv.y = f2bf(acc[2][nt][1]);
        hv.z = f2bf(acc[2][nt][2]); hv.w = f2bf(acc[2][nt][3]);
        *reinterpret_cast<ushort4*>(Vt + ((size_t)(bidx * 64 + h)) * 4096 + t0) = hv;
    }
}

// ---------------------------------------------------------------------------
// Attention math helpers (byte-identical to R13-validated versions)
// ---------------------------------------------------------------------------
DEV void mask_diag(f32x16& st, int q31, int hi) {
#pragma unroll
    for (int reg = 0; reg < 16; ++reg) {
        const int crow = (reg & 3) + 8 * (reg >> 2) + 4 * hi;
        if (crow > q31) st[reg] = -3.0e38f;
    }
}

DEV float max16(const f32x16& a) {
    float m0 = fmaxf(fmaxf(a[0], a[1]), a[2]);
    float m1 = fmaxf(fmaxf(a[3], a[4]), a[5]);
    float m2 = fmaxf(fmaxf(a[6], a[7]), a[8]);
    float m3 = fmaxf(fmaxf(a[9], a[10]), a[11]);
    float m4 = fmaxf(fmaxf(a[12], a[13]), a[14]);
    float m5 = fmaxf(fmaxf(m0, m1), a[15]);
    float m6 = fmaxf(fmaxf(m2, m3), m4);
    return fmaxf(m5, m6);
}

DEV float expsum(f32x16& st, float m) {
    float r0 = 0.f, r1 = 0.f, r2 = 0.f, r3 = 0.f;
#pragma unroll
    for (int g = 0; g < 4; ++g) {
        float p0 = fexp2(st[4 * g + 0] - m);
        float p1 = fexp2(st[4 * g + 1] - m);
        float p2 = fexp2(st[4 * g + 2] - m);
        float p3 = fexp2(st[4 * g + 3] - m);
        st[4 * g + 0] = p0; st[4 * g + 1] = p1;
        st[4 * g + 2] = p2; st[4 * g + 3] = p3;
        r0 += p0; r1 += p1; r2 += p2; r3 += p3;
    }
    return (r0 + r1) + (r2 + r3);
}

DEV void packP(const f32x16& st, bf16x8& pb0, bf16x8& pb1, int hi) {
    u32 A0 = cvt_pk_bf16(st[0], st[1]),  A1 = cvt_pk_bf16(st[2], st[3]);
    u32 A2 = cvt_pk_bf16(st[4], st[5]),  A3 = cvt_pk_bf16(st[6], st[7]);
    u32 A4 = cvt_pk_bf16(st[8], st[9]),  A5 = cvt_pk_bf16(st[10], st[11]);
    u32 A6 = cvt_pk_bf16(st[12], st[13]), A7 = cvt_pk_bf16(st[14], st[15]);
    u32 e0 = __shfl_xor(hi ? A0 : A2, 32, 64);
    u32 e1 = __shfl_xor(hi ? A1 : A3, 32, 64);
    u32 e2 = __shfl_xor(hi ? A4 : A6, 32, 64);
    u32 e3 = __shfl_xor(hi ? A5 : A7, 32, 64);
    u32x4v w0, w1;
    w0[0] = hi ? e0 : A0;
    w0[1] = hi ? e1 : A1;
    w0[2] = hi ? A2 : e0;
    w0[3] = hi ? A3 : e1;
    w1[0] = hi ? e2 : A4;
    w1[1] = hi ? e3 : A5;
    w1[2] = hi ? A6 : e2;
    w1[3] = hi ? A7 : e3;
    pb0 = __builtin_bit_cast(bf16x8, w0);
    pb1 = __builtin_bit_cast(bf16x8, w1);
}

// ---------------------------------------------------------------------------
// Kernel 3: causal flash attention, 4-wave q-block with double-buffered
// LDS-staged K/V.  Block = 4 waves = q-tiles 4j..4j+3 (same batch b),
// iterating the same 32-key subtiles; K (32x64) and V^T (64x32) staged once
// per block per subtile.  Pads 68/36 give 2-way LDS bank aliasing (free).
// Per-wave math identical to R13.  Partials bf16, 16-slot layout.
// ---------------------------------------------------------------------------
__global__ __launch_bounds__(256) void attn_part_kernel(const u16* __restrict__ Q,
                                                        const u16* __restrict__ K,
                                                        const u16* __restrict__ Vt,
                                                        const u32* __restrict__ table,
                                                        u16* __restrict__ Opart,
                                                        float* __restrict__ Mpart,
                                                        float* __restrict__ Lpart) {
    __shared__ __align__(16) u16 Ks[2][32][68];
    __shared__ __align__(16) u16 Vs[2][64][36];

    const int tid = threadIdx.x;
    const int wave = tid >> 6, lane = tid & 63;
    const int q31 = lane & 31, hi = lane >> 5;
    const int bid = blockIdx.x;
    const int b = bid & 3;
    const u32 e = table[bid >> 2];
    const int j = (int)(e & 0xffff);
    const int c = (int)(e >> 16);
    const int qi = 4 * j + wave;              // this wave's q-tile (0..127)
    const int qr0 = qi * 32;
    const int s0 = c * 8;
    const int s1 = min(4 * j + 4, s0 + 8);    // block-uniform
    const int tile = (b << 7) | qi;

    const u16* Qb = Q + (size_t)b * 4096 * 64;
    const u16* Kb = K + (size_t)b * 4096 * 64;
    const u16* Vb = Vt + (size_t)b * 64 * 4096;

    // staging coords (per thread)
    const int kr = tid >> 3, ku = tid & 7;    // K: row 0..31, 16B unit 0..7
    const int vd = tid >> 2, vu = tid & 3;    // V: row 0..63, 16B unit 0..3
    const u16* ksrc = Kb + (size_t)kr * 64 + ku * 8;    // + s*2048
    const u16* vsrc = Vb + (size_t)vd * 4096 + vu * 8;  // + s*32

    bf16x8 qf[4];
#pragma unroll
    for (int kk = 0; kk < 4; ++kk)
        qf[kk] = ld_bf8(Qb + (size_t)(qr0 + q31) * 64 + kk * 16 + hi * 8);

    f32x16 o0, o1;
#pragma unroll
    for (int r = 0; r < 16; ++r) { o0[r] = 0.f; o1[r] = 0.f; }
    float m_run = -1.0e30f, l_run = 0.f;

    // prologue: stage tile s0 into buf0; prefetch tile s0+1 into regs
    ushort4 k0, k1, v0, v1;
    k0 = *reinterpret_cast<const ushort4*>(ksrc + s0 * 2048);
    k1 = *reinterpret_cast<const ushort4*>(ksrc + s0 * 2048 + 4);
    v0 = *reinterpret_cast<const ushort4*>(vsrc + s0 * 32);
    v1 = *reinterpret_cast<const ushort4*>(vsrc + s0 * 32 + 4);
    *reinterpret_cast<ushort4*>(&Ks[0][kr][ku * 8]) = k0;
    *reinterpret_cast<ushort4*>(&Ks[0][kr][ku * 8 + 4]) = k1;
    *reinterpret_cast<ushort4*>(&Vs[0][vd][vu * 8]) = v0;
    *reinterpret_cast<ushort4*>(&Vs[0][vd][vu * 8 + 4]) = v1;
    if (s0 + 1 < s1) {
        k0 = *reinterpret_cast<const ushort4*>(ksrc + (s0 + 1) * 2048);
        k1 = *reinterpret_cast<const ushort4*>(ksrc + (s0 + 1) * 2048 + 4);
        v0 = *reinterpret_cast<const ushort4*>(vsrc + (s0 + 1) * 32);
        v1 = *reinterpret_cast<const ushort4*>(vsrc + (s0 + 1) * 32 + 4);
    }
    __syncthreads();

    for (int s = s0; s < s1; ++s) {
        const int cb = s & 1;
        // write next tile (regs) into the other buffer; its readers finished
        // at the end-of-previous-iteration barrier.
        if (s + 1 < s1) {
            *reinterpret_cast<ushort4*>(&Ks[cb ^ 1][kr][ku * 8]) = k0;
            *reinterpret_cast<ushort4*>(&Ks[cb ^ 1][kr][ku * 8 + 4]) = k1;
            *reinterpret_cast<ushort4*>(&Vs[cb ^ 1][vd][vu * 8]) = v0;
            *reinterpret_cast<ushort4*>(&Vs[cb ^ 1][vd][vu * 8 + 4]) = v1;
        }
        // prefetch tile s+2 into regs (after the ds_writes consumed them)
        if (s + 2 < s1) {
            k0 = *reinterpret_cast<const ushort4*>(ksrc + (s + 2) * 2048);
            k1 = *reinterpret_cast<const ushort4*>(ksrc + (s + 2) * 2048 + 4);
            v0 = *reinterpret_cast<const ushort4*>(vsrc + (s + 2) * 32);
            v1 = *reinterpret_cast<const ushort4*>(vsrc + (s + 2) * 32 + 4);
        }
        // compute (wave-uniform predicate; barrier stays outside)
        if (s <= qi) {
            f32x16 st;
#pragma unroll
            for (int r = 0; r < 16; ++r) st[r] = 0.f;
#pragma unroll
            for (int kk = 0; kk < 4; ++kk) {
                bf16x8 kf = ld_lds8(&Ks[cb][q31][kk * 16 + hi * 8]);
                st = __builtin_amdgcn_mfma_f32_32x32x16_bf16(kf, qf[kk], st, 0, 0, 0);
            }
            if (s == qi) mask_diag(st, q31, hi);

            float pm = max16(st);
            pm = fmaxf(pm, __shfl_xor(pm, 32, 64));
            if (!__all(pm - m_run <= 11.5f)) {
                float mn = fmaxf(m_run, pm);
                float al = fexp2(m_run - mn);
                m_run = mn;
                l_run *= al;
#pragma unroll
                for (int r = 0; r < 16; ++r) { o0[r] *= al; o1[r] *= al; }
            }
            float rs = expsum(st, m_run);
            rs += __shfl_xor(rs, 32, 64);
            l_run += rs;

            bf16x8 p0, p1;
            packP(st, p0, p1, hi);
            bf16x8 va = ld_lds8(&Vs[cb][q31][hi * 8]);
            bf16x8 vb2 = ld_lds8(&Vs[cb][q31][16 + hi * 8]);
            bf16x8 vc = ld_lds8(&Vs[cb][32 + q31][hi * 8]);
            bf16x8 vdq = ld_lds8(&Vs[cb][32 + q31][16 + hi * 8]);
            o0 = __builtin_amdgcn_mfma_f32_32x32x16_bf16(va, p0, o0, 0, 0, 0);
            o0 = __builtin_amdgcn_mfma_f32_32x32x16_bf16(vb2, p1, o0, 0, 0, 0);
            o1 = __builtin_amdgcn_mfma_f32_32x32x16_bf16(vc, p0, o1, 0, 0, 0);
            o1 = __builtin_amdgcn_mfma_f32_32x32x16_bf16(vdq, p1, o1, 0, 0, 0);
        }
        __syncthreads();
    }

    // epilogue: wave writes its partial iff it computed anything (s0 <= qi)
    if (s0 <= qi) {
        const size_t base = (size_t)(tile * 16 + c);
        u16* Op = Opart + base * 2048;
#pragma unroll
        for (int reg = 0; reg < 16; ++reg) {
            const int crow = (reg & 3) + 8 * (reg >> 2) + 4 * hi;
            Op[crow * 32 + q31] = f2bf(o0[reg]);
            Op[(32 + crow) * 32 + q31] = f2bf(o1[reg]);
        }
        if (lane < 32) {
            Mpart[base * 32 + lane] = m_run;
            Lpart[base * 32 + lane] = l_run;
        }
    }
}

// ---------------------------------------------------------------------------
// Kernel 4: merge partials (bf16 Opart).  One block per q-tile (512 blocks).
// Double-buffered LDS + next-chunk prefetch (validated R10/R11/R13).
// nc = floor(qi/8)+1 matches "partial exists iff 8c <= qi".
// ---------------------------------------------------------------------------
__global__ __launch_bounds__(256) void merge_kernel(const u16* __restrict__ Opart,
                                                    const float* __restrict__ Mpart,
                                                    const float* __restrict__ Lpart,
                                                    float* __restrict__ out) {
    __shared__ float ld[2][64 * 33];
    const int tile = blockIdx.x;            // 0..511
    const int tid = threadIdx.x;
    const int q = tid >> 3, dg = tid & 7;
    const int qi = tile & 127;
    const int nkv = qi + 1;
    const int nc = (nkv + 7) >> 3;

    float M = -3.0e38f;
    for (int c = 0; c < nc; ++c)
        M = fmaxf(M, Mpart[(tile * 16 + c) * 32 + q]);

    float L = 0.f;
    float acc[8];
#pragma unroll
    for (int j = 0; j < 8; ++j) acc[j] = 0.f;

    const int drow = tid >> 2;
    const int qq = (tid & 3) * 8;

    u16x8v v = reinterpret_cast<const u16x8v*>(Opart + (size_t)(tile * 16) * 2048)[tid];

    for (int c = 0; c < nc; ++c) {
        const size_t base = (size_t)(tile * 16 + c);
        {
            float* dst = &ld[c & 1][drow * 33 + qq];
#pragma unroll
            for (int j = 0; j < 8; ++j) dst[j] = bf2f(v[j]);
        }
        const int cn = (c + 1 < nc) ? c + 1 : c;
        v = reinterpret_cast<const u16x8v*>(Opart + (size_t)(tile * 16 + cn) * 2048)[tid];

        __syncthreads();
        float w = fexp2(Mpart[base * 32 + q] - M);
        L += w * Lpart[base * 32 + q];
        const float* src = &ld[c & 1][0];
#pragma unroll
        for (int j = 0; j < 8; ++j)
            acc[j] += w * src[(dg * 8 + j) * 33 + q];
    }

    const float inv = 1.0f / L;
    float4 r0, r1;
    r0.x = acc[0] * inv; r0.y = acc[1] * inv; r0.z = acc[2] * inv; r0.w = acc[3] * inv;
    r1.x = acc[4] * inv; r1.y = acc[5] * inv; r1.z = acc[6] * inv; r1.w = acc[7] * inv;
    float4* dst = reinterpret_cast<float4*>(out + ((size_t)(tile * 32 + q)) * 64 + dg * 8);
    dst[0] = r0;
    dst[1] = r1;
}

// ---------------------------------------------------------------------------
extern "C" void kernel_launch(void* const* d_in, const int* in_sizes, int n_in,
                              void* d_out, int out_size, void* d_ws, size_t ws_size,
                              hipStream_t stream) {
    const float* x  = (const float*)d_in[0];
    const float* Wq = (const float*)d_in[1];
    const float* Wk = (const float*)d_in[2];
    const float* Wv = (const float*)d_in[3];
    float* out = (float*)d_out;

    char* ws = (char*)d_ws;
    const size_t MB = 1024 * 1024;
    u16* Qw  = (u16*)(ws);                     // 2 MiB
    u16* Kw  = (u16*)(ws + 2 * MB);            // 2 MiB
    u16* Vtw = (u16*)(ws + 4 * MB);            // 2 MiB
    u16* Wt  = (u16*)(ws + 6 * MB);            // 192 KiB
    u32* table = (u32*)(ws + 7 * MB);          // 1.1 KiB (272 entries)

    u16* Opart = (u16*)(ws + 8 * MB);          // 32 MiB
    float* Mpart = (float*)(ws + 8 * MB + 32 * MB);
    float* Lpart = Mpart + (size_t)16 * 512 * 32;

    prep_kernel<<<386, 256, 0, stream>>>(Wq, Wk, Wv, Wt, table);
    proj_kernel<<<256, 256, 0, stream>>>(x, Wt, Qw, Kw, Vtw);
    attn_part_kernel<<<4 * 272, 256, 0, stream>>>(Qw, Kw, Vtw, table, Opart, Mpart, Lpart);
    merge_kernel<<<512, 256, 0, stream>>>(Opart, Mpart, Lpart, out);
}